// Round 4
// baseline (1738.130 us; speedup 1.0000x reference)
//
#include <hip/hip_runtime.h>
#include <hip/hip_bf16.h>
#include <cstdint>
#include <cstddef>

// Problem dims (fixed)
#define BATCH 2
#define TLEN  2048
#define NHEAD 8
#define HD    128
#define HIDN  1024
#define MTOT  4096          // BATCH*TLEN
#define MAT_ELEMS 1048576   // 1024*1024
#define XELEMS 4194304      // 4096*1024

typedef _Float16 f16;
typedef _Float16 f16x8 __attribute__((ext_vector_type(8)));
typedef float    f32x4 __attribute__((ext_vector_type(4)));

__device__ __forceinline__ float sigmoidf_(float v) { return 1.0f / (1.0f + __expf(-v)); }

// ---------------------------------------------------------------------------
// K0: convert x (fp32) -> f16
__global__ __launch_bounds__(256) void convert_x_kernel(const float* __restrict__ x,
                                                        f16* __restrict__ x16)
{
    int i = (blockIdx.x * 256 + threadIdx.x) * 4;
    float4 v = *(const float4*)(x + i);
    union { f16 h[4]; uint2 u; } pk;
    pk.h[0] = (f16)v.x; pk.h[1] = (f16)v.y; pk.h[2] = (f16)v.z; pk.h[3] = (f16)v.w;
    *(uint2*)(x16 + i) = pk.u;
}

// ---------------------------------------------------------------------------
// K1: transpose-convert the six 1024x1024 weight matrices to f16 WT[mat][n][k]
__global__ __launch_bounds__(256) void transpose_convert_kernel(
    const float* __restrict__ Wq, const float* __restrict__ Wk, const float* __restrict__ Wv,
    const float* __restrict__ Wa, const float* __restrict__ Wg, const float* __restrict__ Wo,
    f16* __restrict__ WT)
{
    __shared__ float tile[32][33];
    int mat = blockIdx.z;
    const float* W = (mat == 0) ? Wq : (mat == 1) ? Wk : (mat == 2) ? Wv
                   : (mat == 3) ? Wa : (mat == 4) ? Wg : Wo;
    int k0 = blockIdx.y * 32, n0 = blockIdx.x * 32;
    int tr = threadIdx.x >> 3;
    int tc = (threadIdx.x & 7) * 4;
    float4 vin = *(const float4*)(W + (size_t)(k0 + tr) * HIDN + n0 + tc);
    tile[tr][tc + 0] = vin.x; tile[tr][tc + 1] = vin.y;
    tile[tr][tc + 2] = vin.z; tile[tr][tc + 3] = vin.w;
    __syncthreads();
    f16* dst = WT + (size_t)(mat * HIDN + n0 + tr) * HIDN + k0 + tc;
    union { f16 h[4]; uint2 u; } pk;
    pk.h[0] = (f16)tile[tc + 0][tr]; pk.h[1] = (f16)tile[tc + 1][tr];
    pk.h[2] = (f16)tile[tc + 2][tr]; pk.h[3] = (f16)tile[tc + 3][tr];
    *(uint2*)dst = pk.u;
}

// ---------------------------------------------------------------------------
// K2/K7: f16 MFMA GEMM, C = A[M,1024] @ BT[n][k]^T, 128x128 tile, BK=32.
template <int MODE>
__global__ __launch_bounds__(256) void gemm_f16(
    const f16* __restrict__ A, const f16* __restrict__ BT,
    float* __restrict__ out_f32,
    f16* __restrict__ qkv_hat, float* __restrict__ a_buf, f16* __restrict__ g16,
    const float* __restrict__ ba)
{
    __shared__ __align__(16) f16 As[128][40];
    __shared__ __align__(16) f16 Bs[128][40];
    int m0 = blockIdx.y * 128;
    int n0 = blockIdx.x * 128;
    int tid = threadIdx.x;
    int w = tid >> 6, lane = tid & 63;
    int L16 = lane & 15, quad = lane >> 4;
    int wm = (w >> 1) * 64, wn = (w & 1) * 64;

    f32x4 acc[4][4];
#pragma unroll
    for (int i = 0; i < 4; ++i)
#pragma unroll
        for (int j = 0; j < 4; ++j) acc[i][j] = (f32x4){0.f, 0.f, 0.f, 0.f};

    int ldr = tid >> 2;
    int ldc = (tid & 3) * 8;

    for (int k0 = 0; k0 < 1024; k0 += 32) {
        uint4 a0 = *(const uint4*)(A + (size_t)(m0 + ldr) * HIDN + k0 + ldc);
        uint4 a1 = *(const uint4*)(A + (size_t)(m0 + ldr + 64) * HIDN + k0 + ldc);
        uint4 b0 = *(const uint4*)(BT + (size_t)(n0 + ldr) * HIDN + k0 + ldc);
        uint4 b1 = *(const uint4*)(BT + (size_t)(n0 + ldr + 64) * HIDN + k0 + ldc);
        __syncthreads();
        *(uint4*)(&As[ldr][ldc]) = a0;
        *(uint4*)(&As[ldr + 64][ldc]) = a1;
        *(uint4*)(&Bs[ldr][ldc]) = b0;
        *(uint4*)(&Bs[ldr + 64][ldc]) = b1;
        __syncthreads();
        f16x8 af[4], bf[4];
#pragma unroll
        for (int i = 0; i < 4; ++i) {
            af[i] = *(const f16x8*)(&As[wm + i * 16 + L16][quad * 8]);
            bf[i] = *(const f16x8*)(&Bs[wn + i * 16 + L16][quad * 8]);
        }
#pragma unroll
        for (int i = 0; i < 4; ++i)
#pragma unroll
            for (int j = 0; j < 4; ++j)
                acc[i][j] = __builtin_amdgcn_mfma_f32_16x16x32_f16(af[i], bf[j], acc[i][j], 0, 0, 0);
    }

#pragma unroll
    for (int i = 0; i < 4; ++i) {
#pragma unroll
        for (int j = 0; j < 4; ++j) {
            f32x4 c = acc[i][j];
            int mbase = m0 + wm + i * 16 + quad * 4;
            int n = n0 + wn + j * 16 + L16;
            if (MODE == 1) {
#pragma unroll
                for (int r = 0; r < 4; ++r)
                    out_f32[(size_t)(mbase + r) * HIDN + n] = c[r];
            } else {
                int mat = n >> 10;
                int nn = n & 1023;
                if (mat < 3) {
#pragma unroll
                    for (int r = 0; r < 4; ++r)
                        qkv_hat[(size_t)mat * XELEMS + (size_t)(mbase + r) * HIDN + nn] = (f16)c[r];
                } else if (mat == 3) {
                    float bav = ba[nn];
#pragma unroll
                    for (int r = 0; r < 4; ++r)
                        a_buf[(size_t)(mbase + r) * HIDN + nn] = sigmoidf_(c[r] + bav);
                } else {
#pragma unroll
                    for (int r = 0; r < 4; ++r)
                        g16[(size_t)(mbase + r) * HIDN + nn] = (f16)sigmoidf_(c[r]);
                }
            }
        }
    }
}

// ---------------------------------------------------------------------------
// K3: beta = sigmoid(x @ Wb + bb), fp32 exact path.
__global__ __launch_bounds__(256) void beta_kernel(const float* __restrict__ x,
                                                   const float* __restrict__ Wb,
                                                   const float* __restrict__ bb,
                                                   float* __restrict__ beta_buf)
{
    int row = blockIdx.x;
    int h = threadIdx.x >> 5, lane = threadIdx.x & 31;
    const float* xr = x + (size_t)row * HIDN;
    float part = 0.f;
    for (int i = lane; i < HIDN; i += 32)
        part += xr[i] * Wb[i * NHEAD + h];
#pragma unroll
    for (int m = 1; m <= 16; m <<= 1) part += __shfl_xor(part, m);
    if (lane == 0)
        beta_buf[(size_t)row * NHEAD + h] = sigmoidf_(part + bb[h]);
}

// ---------------------------------------------------------------------------
// K4: causal depthwise conv (K=4) + SiLU (+ scale for k), f16 output.
__global__ __launch_bounds__(256) void conv_silu_kernel(
    const f16* __restrict__ qkv_hat,
    const float* __restrict__ cqw, const float* __restrict__ cqb,
    const float* __restrict__ ckw, const float* __restrict__ ckb,
    const float* __restrict__ cvw, const float* __restrict__ cvb,
    f16* __restrict__ qkv16)
{
    int z = blockIdx.y;
    int row = blockIdx.x;
    int tloc = row & (TLEN - 1);
    int c4 = threadIdx.x * 4;
    const f16* src = qkv_hat + (size_t)z * XELEMS;
    const float* w  = (z == 0) ? cqw : (z == 1) ? ckw : cvw;
    const float* bi = (z == 0) ? cqb : (z == 1) ? ckb : cvb;

    float xv[4][4];
#pragma unroll
    for (int j = 0; j < 4; ++j) {
        int tt = tloc - 3 + j;
        if (tt >= 0) {
            const f16* p = src + (size_t)(row - 3 + j) * HIDN + c4;
            xv[j][0] = (float)p[0]; xv[j][1] = (float)p[1];
            xv[j][2] = (float)p[2]; xv[j][3] = (float)p[3];
        } else {
            xv[j][0] = xv[j][1] = xv[j][2] = xv[j][3] = 0.f;
        }
    }
    float scale = (z == 1) ? 0.08838834764831845f : 1.0f;  // 128^-0.5 for k
    union { f16 h[4]; uint2 u; } pk;
#pragma unroll
    for (int cc = 0; cc < 4; ++cc) {
        float4 wc = *(const float4*)(w + (size_t)(c4 + cc) * 4);
        float acc = bi[c4 + cc] + wc.x * xv[0][cc] + wc.y * xv[1][cc]
                                 + wc.z * xv[2][cc] + wc.w * xv[3][cc];
        pk.h[cc] = (f16)(acc * sigmoidf_(acc) * scale);
    }
    *(uint2*)(qkv16 + (size_t)z * XELEMS + (size_t)row * HIDN + c4) = pk.u;
}

// ---------------------------------------------------------------------------
// K5: chunked delta-rule scan. One block per (b,h). C=32-step chunks.
// Identity (per v-row, scalars a,beta,v per step, shared k):
//   s_t = P_t s_0 + sum_tau u_tau (P_t/P_tau) k_tau, P_t = prod a
//   u_t = beta_t (v_t - P_{t-1}(s0.k_t) - sum_{tau<t} c_tau G[tau,t])
//   o_t = P_t (s0.q_t) + sum_{tau<=t} c_tau KQ[tau,t]
// where c_tau = u_tau prod_{s=tau+1..t} a_s (maintained by decay each step).
// G=KK^T, KQ=KQ^T, s0K^T, s0Q^T, and S<-P_C*S + C@K are f16 MFMAs.
// S stored in LDS as fp32 scaled by 2^10 (f16-normal range for fragments).
#define SCAN_C 32
#define SSC  1024.0f
#define ISSC 0.0009765625f

__global__ __launch_bounds__(256, 1) void scan_kernel(
    const f16* __restrict__ q16, const f16* __restrict__ k16, const f16* __restrict__ v16,
    const float* __restrict__ a_buf, const float* __restrict__ beta_buf,
    float* __restrict__ o_buf)
{
    __shared__ __align__(16) float Sp[128 * 132];      // scaled state S' = 1024*S
    __shared__ __align__(16) f16   K16s[32 * 136];
    __shared__ __align__(16) f16   Q16s[32 * 136];
    __shared__ __align__(16) f16   V16s[32 * 128];
    __shared__ __align__(16) float Acs[32 * 128];
    __shared__ __align__(16) float Bcs[32];
    __shared__ __align__(16) float Gts[32 * 36];       // Gts[t][tau]
    __shared__ __align__(16) float KQts[32 * 36];      // KQts[t][tau]
    __shared__ __align__(16) float sk0t[32 * 132];     // sk0t[t][v]  (scaled)
    __shared__ __align__(16) float sq0t[32 * 132];
    __shared__ __align__(16) f16   c16s[128 * 40];     // c16s[v][tau] (scaled)
    __shared__ __align__(16) float PCs[128];

    int bh = blockIdx.x;
    int b = bh >> 3, h = bh & 7;
    int tid = threadIdx.x;
    int w = tid >> 6, lane = tid & 63, L16 = lane & 15, quad = lane >> 4;
    const size_t rowbase = (size_t)(b * TLEN) * HIDN + h * HD;

    for (int i = tid; i < 128 * 132; i += 256) Sp[i] = 0.f;
    __syncthreads();

    for (int ch = 0; ch < TLEN / SCAN_C; ++ch) {
        int t0 = ch * SCAN_C;

        // ---- Phase A1: global -> LDS staging ----
        {
            int t = tid >> 3, seg = (tid & 7) * 16;
            size_t gaddr = rowbase + (size_t)(t0 + t) * HIDN + seg;
            *(uint4*)(&K16s[t * 136 + seg])     = *(const uint4*)(k16 + gaddr);
            *(uint4*)(&K16s[t * 136 + seg + 8]) = *(const uint4*)(k16 + gaddr + 8);
            *(uint4*)(&Q16s[t * 136 + seg])     = *(const uint4*)(q16 + gaddr);
            *(uint4*)(&Q16s[t * 136 + seg + 8]) = *(const uint4*)(q16 + gaddr + 8);
            *(uint4*)(&V16s[t * 128 + seg])     = *(const uint4*)(v16 + gaddr);
            *(uint4*)(&V16s[t * 128 + seg + 8]) = *(const uint4*)(v16 + gaddr + 8);
#pragma unroll
            for (int j = 0; j < 4; ++j) {
                int idx = tid + 256 * j;
                int ta = idx >> 5, c4 = (idx & 31) * 4;
                *(float4*)(&Acs[ta * 128 + c4]) =
                    *(const float4*)(a_buf + rowbase + (size_t)(t0 + ta) * HIDN + c4);
            }
            if (tid < 32)
                Bcs[tid] = beta_buf[((size_t)(b * TLEN) + t0 + tid) * NHEAD + h];
        }
        __syncthreads();

        // ---- Phase A2: MFMA G, KQ, sk0, sq0 ----
        {
            f16x8 bK[2][4], bQ[2][4];
#pragma unroll
            for (int nt = 0; nt < 2; ++nt)
#pragma unroll
                for (int kk = 0; kk < 4; ++kk) {
                    bK[nt][kk] = *(const f16x8*)(&K16s[(nt * 16 + L16) * 136 + kk * 32 + quad * 8]);
                    bQ[nt][kk] = *(const f16x8*)(&Q16s[(nt * 16 + L16) * 136 + kk * 32 + quad * 8]);
                }
            f32x4 aK[2][2], aQ[2][2];
#pragma unroll
            for (int i = 0; i < 2; ++i)
#pragma unroll
                for (int j = 0; j < 2; ++j) { aK[i][j] = (f32x4){0,0,0,0}; aQ[i][j] = (f32x4){0,0,0,0}; }
#pragma unroll
            for (int mt = 0; mt < 2; ++mt) {
                int m0 = w * 32 + mt * 16;
#pragma unroll
                for (int kk = 0; kk < 4; ++kk) {
                    float4 s0 = *(const float4*)(&Sp[(m0 + L16) * 132 + kk * 32 + quad * 8]);
                    float4 s1 = *(const float4*)(&Sp[(m0 + L16) * 132 + kk * 32 + quad * 8 + 4]);
                    f16x8 af;
                    af[0] = (f16)s0.x; af[1] = (f16)s0.y; af[2] = (f16)s0.z; af[3] = (f16)s0.w;
                    af[4] = (f16)s1.x; af[5] = (f16)s1.y; af[6] = (f16)s1.z; af[7] = (f16)s1.w;
#pragma unroll
                    for (int nt = 0; nt < 2; ++nt) {
                        aK[mt][nt] = __builtin_amdgcn_mfma_f32_16x16x32_f16(af, bK[nt][kk], aK[mt][nt], 0, 0, 0);
                        aQ[mt][nt] = __builtin_amdgcn_mfma_f32_16x16x32_f16(af, bQ[nt][kk], aQ[mt][nt], 0, 0, 0);
                    }
                }
            }
#pragma unroll
            for (int mt = 0; mt < 2; ++mt)
#pragma unroll
                for (int nt = 0; nt < 2; ++nt)
#pragma unroll
                    for (int r = 0; r < 4; ++r) {
                        int v = w * 32 + mt * 16 + quad * 4 + r;
                        int t = nt * 16 + L16;
                        sk0t[t * 132 + v] = aK[mt][nt][r];
                        sq0t[t * 132 + v] = aQ[mt][nt][r];
                    }
            if (w < 2) {
                const f16* Br = (w == 0) ? K16s : Q16s;
                float* dst = (w == 0) ? Gts : KQts;
                f32x4 acc[2][2];
#pragma unroll
                for (int i = 0; i < 2; ++i)
#pragma unroll
                    for (int j = 0; j < 2; ++j) acc[i][j] = (f32x4){0,0,0,0};
#pragma unroll
                for (int kk = 0; kk < 4; ++kk) {
                    f16x8 a0 = *(const f16x8*)(&K16s[(L16) * 136 + kk * 32 + quad * 8]);
                    f16x8 a1 = *(const f16x8*)(&K16s[(16 + L16) * 136 + kk * 32 + quad * 8]);
                    f16x8 b0 = *(const f16x8*)(&Br[(L16) * 136 + kk * 32 + quad * 8]);
                    f16x8 b1 = *(const f16x8*)(&Br[(16 + L16) * 136 + kk * 32 + quad * 8]);
                    acc[0][0] = __builtin_amdgcn_mfma_f32_16x16x32_f16(a0, b0, acc[0][0], 0, 0, 0);
                    acc[0][1] = __builtin_amdgcn_mfma_f32_16x16x32_f16(a0, b1, acc[0][1], 0, 0, 0);
                    acc[1][0] = __builtin_amdgcn_mfma_f32_16x16x32_f16(a1, b0, acc[1][0], 0, 0, 0);
                    acc[1][1] = __builtin_amdgcn_mfma_f32_16x16x32_f16(a1, b1, acc[1][1], 0, 0, 0);
                }
#pragma unroll
                for (int ti = 0; ti < 2; ++ti)
#pragma unroll
                    for (int tj = 0; tj < 2; ++tj)
#pragma unroll
                        for (int r = 0; r < 4; ++r) {
                            int tau = ti * 16 + quad * 4 + r;
                            int t = tj * 16 + L16;
                            dst[t * 36 + tau] = acc[ti][tj][r];
                        }
            }
        }
        __syncthreads();

        // ---- Phase B: serial triangular solve (128 lanes = 128 v-rows) ----
        if (tid < 128) {
            int v = tid;
            float c[SCAN_C];
            float P = 1.f;
#pragma unroll
            for (int t = 0; t < SCAN_C; ++t) {
                union { float4 v4[8]; float f[32]; } gU, qU;
                const int nq = (t + 4) >> 2;
                const int ng = (t + 3) >> 2;
#pragma unroll
                for (int i = 0; i < 8; ++i) {
                    if (i < nq) qU.v4[i] = *(const float4*)(&KQts[t * 36 + 4 * i]);
                    if (i < ng) gU.v4[i] = *(const float4*)(&Gts[t * 36 + 4 * i]);
                }
                float acc = 0.f;
#pragma unroll
                for (int tau = 0; tau < SCAN_C; ++tau)
                    if (tau < t) acc = fmaf(c[tau], gU.f[tau], acc);
                float sk = sk0t[t * 132 + v] * ISSC;
                float vv = (float)V16s[t * 128 + v];
                float u = Bcs[t] * (vv - fmaf(P, sk, acc));
                float at = Acs[t * 128 + v];
                P *= at;
#pragma unroll
                for (int tau = 0; tau < SCAN_C; ++tau)
                    if (tau < t) c[tau] *= at;
                c[t] = u;
                float o = P * (sq0t[t * 132 + v] * ISSC);
#pragma unroll
                for (int tau = 0; tau < SCAN_C; ++tau)
                    if (tau <= t) o = fmaf(c[tau], qU.f[tau], o);
                o_buf[rowbase + (size_t)(t0 + t) * HIDN + v] = o;
            }
#pragma unroll
            for (int j = 0; j < 4; ++j) {
                union { f16 e[8]; uint4 u4; } pk;
#pragma unroll
                for (int e = 0; e < 8; ++e) pk.e[e] = (f16)(c[j * 8 + e] * SSC);
                *(uint4*)(&c16s[v * 40 + j * 8]) = pk.u4;
            }
            PCs[v] = P;
        }
        __syncthreads();

        // ---- Phase C: S' <- PC * S' + Ccoef @ K ----
        if (ch < TLEN / SCAN_C - 1) {
#pragma unroll
            for (int mi = 0; mi < 2; ++mi) {
                int mt = w + mi * 4;
                f16x8 af = *(const f16x8*)(&c16s[(mt * 16 + L16) * 40 + quad * 8]);
#pragma unroll
                for (int nt = 0; nt < 8; ++nt) {
                    union { f16 e[8]; f16x8 v8; } bu;
#pragma unroll
                    for (int j = 0; j < 8; ++j)
                        bu.e[j] = K16s[(quad * 8 + j) * 136 + nt * 16 + L16];
                    f32x4 d = __builtin_amdgcn_mfma_f32_16x16x32_f16(af, bu.v8, (f32x4){0,0,0,0}, 0, 0, 0);
#pragma unroll
                    for (int r = 0; r < 4; ++r) {
                        int vv = mt * 16 + quad * 4 + r;
                        int kk2 = nt * 16 + L16;
                        Sp[vv * 132 + kk2] = PCs[vv] * Sp[vv * 132 + kk2] + d[r];
                    }
                }
            }
        }
        __syncthreads();
    }
}

// ---------------------------------------------------------------------------
// K6: LayerNorm over head dim, * g, -> f16 for output GEMM
__global__ __launch_bounds__(256) void ln_gate_kernel(
    const float* __restrict__ o_buf, const f16* __restrict__ g16,
    const float* __restrict__ lng, const float* __restrict__ lnb,
    f16* __restrict__ og16)
{
    int row = blockIdx.x;
    int h = threadIdx.x >> 5, lane = threadIdx.x & 31;
    size_t base = (size_t)row * HIDN + h * HD + lane * 4;
    float4 x = *(const float4*)(o_buf + base);
    float s  = x.x + x.y + x.z + x.w;
    float sq = x.x * x.x + x.y * x.y + x.z * x.z + x.w * x.w;
#pragma unroll
    for (int m = 1; m <= 16; m <<= 1) {
        s  += __shfl_xor(s, m);
        sq += __shfl_xor(sq, m);
    }
    float mu  = s * (1.0f / 128.0f);
    float var = sq * (1.0f / 128.0f) - mu * mu;
    float inv = 1.0f / sqrtf(var + 1e-5f);
    int d = lane * 4;
    const float* xp = (const float*)&x;
    union { f16 h4[4]; uint2 u; } pk;
#pragma unroll
    for (int j = 0; j < 4; ++j) {
        float on = (xp[j] - mu) * inv * lng[d + j] + lnb[d + j];
        pk.h4[j] = (f16)(on * (float)g16[base + j]);
    }
    *(uint2*)(og16 + base) = pk.u;
}

// ---------------------------------------------------------------------------
extern "C" void kernel_launch(void* const* d_in, const int* in_sizes, int n_in,
                              void* d_out, int out_size, void* d_ws, size_t ws_size,
                              hipStream_t stream)
{
    (void)in_sizes; (void)n_in; (void)out_size; (void)ws_size;
    const float* x   = (const float*)d_in[0];
    const float* Wq  = (const float*)d_in[1];
    const float* Wk  = (const float*)d_in[2];
    const float* Wv  = (const float*)d_in[3];
    const float* Wa  = (const float*)d_in[4];
    const float* ba  = (const float*)d_in[5];
    const float* Wb  = (const float*)d_in[6];
    const float* bb  = (const float*)d_in[7];
    const float* Wg  = (const float*)d_in[8];
    const float* Wo  = (const float*)d_in[9];
    const float* cqw = (const float*)d_in[10];
    const float* cqb = (const float*)d_in[11];
    const float* ckw = (const float*)d_in[12];
    const float* ckb = (const float*)d_in[13];
    const float* cvw = (const float*)d_in[14];
    const float* cvb = (const float*)d_in[15];
    const float* lng = (const float*)d_in[16];
    const float* lnb = (const float*)d_in[17];
    float* out = (float*)d_out;

    char* ws = (char*)d_ws;
    f16*   x16      = (f16*)(ws + 0);                 //  8,388,608 B
    f16*   WT       = (f16*)(ws + 8388608);           // 12,582,912 B
    f16*   qkvh     = (f16*)(ws + 20971520);          // 25,165,824 B
    f16*   qkv16    = (f16*)(ws + 46137344);          // 25,165,824 B (f16 q,k,v post-conv)
    float* a_buf    = (float*)(ws + 96468992);        // 16,777,216 B
    f16*   g16      = (f16*)(ws + 113246208);         //  8,388,608 B
    float* beta_buf = (float*)(ws + 121634816);       //    131,072 B
    float* o_buf    = (float*)(ws + 121765888);       // 16,777,216 B
    f16*   og16     = (f16*)(ws + 138543104);         //  8,388,608 B

    convert_x_kernel<<<dim3(4096), dim3(256), 0, stream>>>(x, x16);
    transpose_convert_kernel<<<dim3(32, 32, 6), dim3(256), 0, stream>>>(Wq, Wk, Wv, Wa, Wg, Wo, WT);
    gemm_f16<0><<<dim3(40, 32), dim3(256), 0, stream>>>(x16, WT, nullptr, qkvh, a_buf, g16, ba);
    beta_kernel<<<dim3(4096), dim3(256), 0, stream>>>(x, Wb, bb, beta_buf);
    conv_silu_kernel<<<dim3(4096, 3), dim3(256), 0, stream>>>(qkvh, cqw, cqb, ckw, ckb, cvw, cvb, qkv16);
    scan_kernel<<<dim3(16), dim3(256), 0, stream>>>(
        qkv16, qkv16 + XELEMS, qkv16 + 2 * (size_t)XELEMS, a_buf, beta_buf, o_buf);
    ln_gate_kernel<<<dim3(4096), dim3(256), 0, stream>>>(o_buf, g16, lng, lnb, og16);
    gemm_f16<1><<<dim3(8, 32), dim3(256), 0, stream>>>(og16, WT + 5 * (size_t)MAT_ELEMS, out,
                                                       nullptr, nullptr, nullptr, nullptr);
}

// Round 5
// 727.588 us; speedup vs baseline: 2.3889x; 2.3889x over previous
//
#include <hip/hip_runtime.h>
#include <hip/hip_bf16.h>
#include <cstdint>
#include <cstddef>

// Problem dims (fixed)
#define BATCH 2
#define TLEN  2048
#define NHEAD 8
#define HD    128
#define HIDN  1024
#define MTOT  4096          // BATCH*TLEN
#define MAT_ELEMS 1048576   // 1024*1024
#define XELEMS 4194304      // 4096*1024

typedef _Float16 f16;
typedef _Float16 f16x8 __attribute__((ext_vector_type(8)));
typedef float    f32x4 __attribute__((ext_vector_type(4)));

__device__ __forceinline__ float sigmoidf_(float v) { return 1.0f / (1.0f + __expf(-v)); }

// ---------------------------------------------------------------------------
// K0: convert x (fp32) -> f16
__global__ __launch_bounds__(256) void convert_x_kernel(const float* __restrict__ x,
                                                        f16* __restrict__ x16)
{
    int i = (blockIdx.x * 256 + threadIdx.x) * 4;
    float4 v = *(const float4*)(x + i);
    union { f16 h[4]; uint2 u; } pk;
    pk.h[0] = (f16)v.x; pk.h[1] = (f16)v.y; pk.h[2] = (f16)v.z; pk.h[3] = (f16)v.w;
    *(uint2*)(x16 + i) = pk.u;
}

// ---------------------------------------------------------------------------
// K1: transpose-convert the six 1024x1024 weight matrices to f16 WT[mat][n][k]
__global__ __launch_bounds__(256) void transpose_convert_kernel(
    const float* __restrict__ Wq, const float* __restrict__ Wk, const float* __restrict__ Wv,
    const float* __restrict__ Wa, const float* __restrict__ Wg, const float* __restrict__ Wo,
    f16* __restrict__ WT)
{
    __shared__ float tile[32][33];
    int mat = blockIdx.z;
    const float* W = (mat == 0) ? Wq : (mat == 1) ? Wk : (mat == 2) ? Wv
                   : (mat == 3) ? Wa : (mat == 4) ? Wg : Wo;
    int k0 = blockIdx.y * 32, n0 = blockIdx.x * 32;
    int tr = threadIdx.x >> 3;
    int tc = (threadIdx.x & 7) * 4;
    float4 vin = *(const float4*)(W + (size_t)(k0 + tr) * HIDN + n0 + tc);
    tile[tr][tc + 0] = vin.x; tile[tr][tc + 1] = vin.y;
    tile[tr][tc + 2] = vin.z; tile[tr][tc + 3] = vin.w;
    __syncthreads();
    f16* dst = WT + (size_t)(mat * HIDN + n0 + tr) * HIDN + k0 + tc;
    union { f16 h[4]; uint2 u; } pk;
    pk.h[0] = (f16)tile[tc + 0][tr]; pk.h[1] = (f16)tile[tc + 1][tr];
    pk.h[2] = (f16)tile[tc + 2][tr]; pk.h[3] = (f16)tile[tc + 3][tr];
    *(uint2*)dst = pk.u;
}

// ---------------------------------------------------------------------------
// K2/K7: f16 MFMA GEMM, C = A[M,1024] @ BT[n][k]^T, 128x128 tile, BK=32.
template <int MODE>
__global__ __launch_bounds__(256) void gemm_f16(
    const f16* __restrict__ A, const f16* __restrict__ BT,
    float* __restrict__ out_f32,
    f16* __restrict__ qkv_hat, float* __restrict__ a_buf, f16* __restrict__ g16,
    const float* __restrict__ ba)
{
    __shared__ __align__(16) f16 As[128][40];
    __shared__ __align__(16) f16 Bs[128][40];
    int m0 = blockIdx.y * 128;
    int n0 = blockIdx.x * 128;
    int tid = threadIdx.x;
    int w = tid >> 6, lane = tid & 63;
    int L16 = lane & 15, quad = lane >> 4;
    int wm = (w >> 1) * 64, wn = (w & 1) * 64;

    f32x4 acc[4][4];
#pragma unroll
    for (int i = 0; i < 4; ++i)
#pragma unroll
        for (int j = 0; j < 4; ++j) acc[i][j] = (f32x4){0.f, 0.f, 0.f, 0.f};

    int ldr = tid >> 2;
    int ldc = (tid & 3) * 8;

    for (int k0 = 0; k0 < 1024; k0 += 32) {
        uint4 a0 = *(const uint4*)(A + (size_t)(m0 + ldr) * HIDN + k0 + ldc);
        uint4 a1 = *(const uint4*)(A + (size_t)(m0 + ldr + 64) * HIDN + k0 + ldc);
        uint4 b0 = *(const uint4*)(BT + (size_t)(n0 + ldr) * HIDN + k0 + ldc);
        uint4 b1 = *(const uint4*)(BT + (size_t)(n0 + ldr + 64) * HIDN + k0 + ldc);
        __syncthreads();
        *(uint4*)(&As[ldr][ldc]) = a0;
        *(uint4*)(&As[ldr + 64][ldc]) = a1;
        *(uint4*)(&Bs[ldr][ldc]) = b0;
        *(uint4*)(&Bs[ldr + 64][ldc]) = b1;
        __syncthreads();
        f16x8 af[4], bf[4];
#pragma unroll
        for (int i = 0; i < 4; ++i) {
            af[i] = *(const f16x8*)(&As[wm + i * 16 + L16][quad * 8]);
            bf[i] = *(const f16x8*)(&Bs[wn + i * 16 + L16][quad * 8]);
        }
#pragma unroll
        for (int i = 0; i < 4; ++i)
#pragma unroll
            for (int j = 0; j < 4; ++j)
                acc[i][j] = __builtin_amdgcn_mfma_f32_16x16x32_f16(af[i], bf[j], acc[i][j], 0, 0, 0);
    }

#pragma unroll
    for (int i = 0; i < 4; ++i) {
#pragma unroll
        for (int j = 0; j < 4; ++j) {
            f32x4 c = acc[i][j];
            int mbase = m0 + wm + i * 16 + quad * 4;
            int n = n0 + wn + j * 16 + L16;
            if (MODE == 1) {
#pragma unroll
                for (int r = 0; r < 4; ++r)
                    out_f32[(size_t)(mbase + r) * HIDN + n] = c[r];
            } else {
                int mat = n >> 10;
                int nn = n & 1023;
                if (mat < 3) {
#pragma unroll
                    for (int r = 0; r < 4; ++r)
                        qkv_hat[(size_t)mat * XELEMS + (size_t)(mbase + r) * HIDN + nn] = (f16)c[r];
                } else if (mat == 3) {
                    float bav = ba[nn];
#pragma unroll
                    for (int r = 0; r < 4; ++r)
                        a_buf[(size_t)(mbase + r) * HIDN + nn] = sigmoidf_(c[r] + bav);
                } else {
#pragma unroll
                    for (int r = 0; r < 4; ++r)
                        g16[(size_t)(mbase + r) * HIDN + nn] = (f16)sigmoidf_(c[r]);
                }
            }
        }
    }
}

// ---------------------------------------------------------------------------
// K3: beta = sigmoid(x @ Wb + bb), fp32 exact path.
__global__ __launch_bounds__(256) void beta_kernel(const float* __restrict__ x,
                                                   const float* __restrict__ Wb,
                                                   const float* __restrict__ bb,
                                                   float* __restrict__ beta_buf)
{
    int row = blockIdx.x;
    int h = threadIdx.x >> 5, lane = threadIdx.x & 31;
    const float* xr = x + (size_t)row * HIDN;
    float part = 0.f;
    for (int i = lane; i < HIDN; i += 32)
        part += xr[i] * Wb[i * NHEAD + h];
#pragma unroll
    for (int m = 1; m <= 16; m <<= 1) part += __shfl_xor(part, m);
    if (lane == 0)
        beta_buf[(size_t)row * NHEAD + h] = sigmoidf_(part + bb[h]);
}

// ---------------------------------------------------------------------------
// K4: causal depthwise conv (K=4) + SiLU (+ scale for k), f16 output.
__global__ __launch_bounds__(256) void conv_silu_kernel(
    const f16* __restrict__ qkv_hat,
    const float* __restrict__ cqw, const float* __restrict__ cqb,
    const float* __restrict__ ckw, const float* __restrict__ ckb,
    const float* __restrict__ cvw, const float* __restrict__ cvb,
    f16* __restrict__ qkv16)
{
    int z = blockIdx.y;
    int row = blockIdx.x;
    int tloc = row & (TLEN - 1);
    int c4 = threadIdx.x * 4;
    const f16* src = qkv_hat + (size_t)z * XELEMS;
    const float* w  = (z == 0) ? cqw : (z == 1) ? ckw : cvw;
    const float* bi = (z == 0) ? cqb : (z == 1) ? ckb : cvb;

    float xv[4][4];
#pragma unroll
    for (int j = 0; j < 4; ++j) {
        int tt = tloc - 3 + j;
        if (tt >= 0) {
            const f16* p = src + (size_t)(row - 3 + j) * HIDN + c4;
            xv[j][0] = (float)p[0]; xv[j][1] = (float)p[1];
            xv[j][2] = (float)p[2]; xv[j][3] = (float)p[3];
        } else {
            xv[j][0] = xv[j][1] = xv[j][2] = xv[j][3] = 0.f;
        }
    }
    float scale = (z == 1) ? 0.08838834764831845f : 1.0f;  // 128^-0.5 for k
    union { f16 h[4]; uint2 u; } pk;
#pragma unroll
    for (int cc = 0; cc < 4; ++cc) {
        float4 wc = *(const float4*)(w + (size_t)(c4 + cc) * 4);
        float acc = bi[c4 + cc] + wc.x * xv[0][cc] + wc.y * xv[1][cc]
                                 + wc.z * xv[2][cc] + wc.w * xv[3][cc];
        pk.h[cc] = (f16)(acc * sigmoidf_(acc) * scale);
    }
    *(uint2*)(qkv16 + (size_t)z * XELEMS + (size_t)row * HIDN + c4) = pk.u;
}

// ---------------------------------------------------------------------------
// K5: chunked delta-rule scan, v-split. Grid = (8 vsplit, 16 bh); one wave
// (64 thr) per block owns a 16-v-row slice of the 128x128 state (fp32 x1024
// in LDS). Per 32-step chunk: G=KK^T, KQ=KQ^T, s0K^T, s0Q^T via 48 MFMAs
// (frags straight from prefetched regs); triangular solve with c[] in regs
// (4 lanes per v-row, quad_perm DPP reductions, broadcast b128 G/KQ rows);
// state update via 8 MFMAs. Next chunk's k/q/a/v/beta prefetched into regs
// during the solve.
#define SCAN_C 32
#define SSC  1024.0f
#define ISSC 0.0009765625f

__global__ __launch_bounds__(64) void scan_kernel(
    const f16* __restrict__ q16, const f16* __restrict__ k16, const f16* __restrict__ v16,
    const float* __restrict__ a_buf, const float* __restrict__ beta_buf,
    float* __restrict__ o_buf)
{
    __shared__ __align__(16) float Sp[16 * 132];    // state slice, x1024
    __shared__ __align__(16) f16   Ks[32 * 136];    // K chunk [t][k]
    __shared__ __align__(16) float Gts[32 * 36];    // Gts[t][tau] = k_tau . k_t
    __shared__ __align__(16) float KQts[32 * 36];   // KQts[t][tau] = k_tau . q_t
    __shared__ __align__(16) float sk0t[32 * 20];   // [t][v] (x1024)
    __shared__ __align__(16) float sq0t[32 * 20];
    __shared__ __align__(16) float avbv[32 * 40];   // [t][v*2+{a, beta*v}]
    __shared__ __align__(16) float Bts[32];
    __shared__ __align__(16) f16   c16s[16 * 40];   // [v][tau], x1024
    __shared__ __align__(16) float PCs[16];

    int bh = blockIdx.y;
    int b = bh >> 3, h = bh & 7;
    int v0 = blockIdx.x * 16;
    int lane = threadIdx.x;
    int L16 = lane & 15, quad = lane >> 4;
    int vl = lane >> 2, li = lane & 3;
    int t_av = lane >> 1, halfsel = lane & 1;
    const size_t rowbase = (size_t)(b * TLEN) * HIDN + h * HD;

    // prefetch registers for one chunk
    f16x8 kf[2][4], qf[2][4];
    float4 ar0, ar1; uint4 vr; float betr = 0.f;

    auto prefetch = [&](int t0) {
#pragma unroll
        for (int nt = 0; nt < 2; ++nt)
#pragma unroll
            for (int kk = 0; kk < 4; ++kk) {
                size_t g = rowbase + (size_t)(t0 + nt * 16 + L16) * HIDN + kk * 32 + quad * 8;
                kf[nt][kk] = *(const f16x8*)(k16 + g);
                qf[nt][kk] = *(const f16x8*)(q16 + g);
            }
        size_t ga = rowbase + (size_t)(t0 + t_av) * HIDN + v0 + halfsel * 8;
        ar0 = *(const float4*)(a_buf + ga);
        ar1 = *(const float4*)(a_buf + ga + 4);
        vr  = *(const uint4*)(v16 + ga);
        betr = beta_buf[((size_t)(b * TLEN) + t0 + t_av) * NHEAD + h];
    };

    auto stage = [&]() {
#pragma unroll
        for (int nt = 0; nt < 2; ++nt)
#pragma unroll
            for (int kk = 0; kk < 4; ++kk)
                *(f16x8*)(&Ks[(nt * 16 + L16) * 136 + kk * 32 + quad * 8]) = kf[nt][kk];
        const f16* vh = (const f16*)&vr;
        const float* af = (const float*)&ar0;   // ar0,ar1 contiguous? not guaranteed; handle split
        float* dst = &avbv[t_av * 40 + halfsel * 16];
#pragma unroll
        for (int e = 0; e < 4; ++e) {
            float2 w2; w2.x = ((const float*)&ar0)[e]; w2.y = betr * (float)vh[e];
            *(float2*)(dst + e * 2) = w2;
        }
#pragma unroll
        for (int e = 0; e < 4; ++e) {
            float2 w2; w2.x = ((const float*)&ar1)[e]; w2.y = betr * (float)vh[4 + e];
            *(float2*)(dst + 8 + e * 2) = w2;
        }
        (void)af;
        if (halfsel == 0) Bts[t_av] = betr;
    };

    auto computeMM = [&]() {
        f32x4 accG[2][2], accKQ[2][2], accK[2], accQ[2];
#pragma unroll
        for (int i = 0; i < 2; ++i) {
            accK[i] = (f32x4){0, 0, 0, 0}; accQ[i] = (f32x4){0, 0, 0, 0};
#pragma unroll
            for (int j = 0; j < 2; ++j) { accG[i][j] = (f32x4){0, 0, 0, 0}; accKQ[i][j] = (f32x4){0, 0, 0, 0}; }
        }
#pragma unroll
        for (int kk = 0; kk < 4; ++kk) {
            float4 s0 = *(const float4*)(&Sp[L16 * 132 + kk * 32 + quad * 8]);
            float4 s1 = *(const float4*)(&Sp[L16 * 132 + kk * 32 + quad * 8 + 4]);
            f16x8 sf;
            sf[0] = (f16)s0.x; sf[1] = (f16)s0.y; sf[2] = (f16)s0.z; sf[3] = (f16)s0.w;
            sf[4] = (f16)s1.x; sf[5] = (f16)s1.y; sf[6] = (f16)s1.z; sf[7] = (f16)s1.w;
#pragma unroll
            for (int nt = 0; nt < 2; ++nt) {
                accK[nt] = __builtin_amdgcn_mfma_f32_16x16x32_f16(sf, kf[nt][kk], accK[nt], 0, 0, 0);
                accQ[nt] = __builtin_amdgcn_mfma_f32_16x16x32_f16(sf, qf[nt][kk], accQ[nt], 0, 0, 0);
#pragma unroll
                for (int mt = 0; mt < 2; ++mt) {
                    accG[mt][nt]  = __builtin_amdgcn_mfma_f32_16x16x32_f16(kf[mt][kk], kf[nt][kk], accG[mt][nt], 0, 0, 0);
                    accKQ[mt][nt] = __builtin_amdgcn_mfma_f32_16x16x32_f16(kf[mt][kk], qf[nt][kk], accKQ[mt][nt], 0, 0, 0);
                }
            }
        }
#pragma unroll
        for (int nt = 0; nt < 2; ++nt) {
            int t = nt * 16 + L16;
#pragma unroll
            for (int mt = 0; mt < 2; ++mt) {
                *(f32x4*)(&Gts[t * 36 + mt * 16 + quad * 4])  = accG[mt][nt];
                *(f32x4*)(&KQts[t * 36 + mt * 16 + quad * 4]) = accKQ[mt][nt];
            }
            *(f32x4*)(&sk0t[t * 20 + quad * 4]) = accK[nt];
            *(f32x4*)(&sq0t[t * 20 + quad * 4]) = accQ[nt];
        }
    };

    auto stateUpdate = [&]() {
        f16x8 ca = *(const f16x8*)(&c16s[L16 * 40 + quad * 8]);
        float pr[4];
#pragma unroll
        for (int r = 0; r < 4; ++r) pr[r] = PCs[quad * 4 + r];
#pragma unroll
        for (int kt = 0; kt < 8; ++kt) {
            union { f16 e[8]; f16x8 v8; } bu;
#pragma unroll
            for (int j = 0; j < 8; ++j)
                bu.e[j] = Ks[(quad * 8 + j) * 136 + kt * 16 + L16];
            f32x4 d = __builtin_amdgcn_mfma_f32_16x16x32_f16(ca, bu.v8, (f32x4){0, 0, 0, 0}, 0, 0, 0);
#pragma unroll
            for (int r = 0; r < 4; ++r) {
                int idx = (quad * 4 + r) * 132 + kt * 16 + L16;
                Sp[idx] = pr[r] * Sp[idx] + d[r];
            }
        }
    };

    prefetch(0);
    for (int i = lane; i < 16 * 132; i += 64) Sp[i] = 0.f;
    __syncthreads();

    const size_t obase = rowbase + v0 + vl;

    for (int ch = 0; ch < TLEN / SCAN_C; ++ch) {
        int t0 = ch * SCAN_C;
        stage();
        __syncthreads();
        computeMM();
        if (ch < TLEN / SCAN_C - 1) prefetch(t0 + SCAN_C);
        __syncthreads();

        // ---- triangular solve, c[] in registers ----
        {
            float c[8];
#pragma unroll
            for (int j = 0; j < 8; ++j) c[j] = 0.f;
            float P = 1.f;
#pragma unroll
            for (int t = 0; t < SCAN_C; ++t) {
                float4 g0 = *(const float4*)(&Gts[t * 36 + li * 8]);
                float4 g1 = *(const float4*)(&Gts[t * 36 + li * 8 + 4]);
                float4 h0 = *(const float4*)(&KQts[t * 36 + li * 8]);
                float4 h1 = *(const float4*)(&KQts[t * 36 + li * 8 + 4]);
                float2 ab = *(const float2*)(&avbv[t * 40 + vl * 2]);
                float bt2 = Bts[t];
                float sk = sk0t[t * 20 + vl] * ISSC;
                float sq = sq0t[t * 20 + vl] * ISSC;
                float kqtt = KQts[t * 36 + t];
                float pG = (fmaf(c[0], g0.x, c[1] * g0.y) + fmaf(c[2], g0.z, c[3] * g0.w))
                         + (fmaf(c[4], g1.x, c[5] * g1.y) + fmaf(c[6], g1.z, c[7] * g1.w));
                float pO = (fmaf(c[0], h0.x, c[1] * h0.y) + fmaf(c[2], h0.z, c[3] * h0.w))
                         + (fmaf(c[4], h1.x, c[5] * h1.y) + fmaf(c[6], h1.z, c[7] * h1.w));
                int tmp;
                tmp = __builtin_amdgcn_update_dpp(0, __float_as_int(pG), 0xB1, 0xF, 0xF, true);
                pG += __int_as_float(tmp);
                tmp = __builtin_amdgcn_update_dpp(0, __float_as_int(pG), 0x4E, 0xF, 0xF, true);
                pG += __int_as_float(tmp);
                tmp = __builtin_amdgcn_update_dpp(0, __float_as_int(pO), 0xB1, 0xF, 0xF, true);
                pO += __int_as_float(tmp);
                tmp = __builtin_amdgcn_update_dpp(0, __float_as_int(pO), 0x4E, 0xF, 0xF, true);
                pO += __int_as_float(tmp);

                float x = fmaf(P, sk, pG);
                float u = fmaf(-bt2, x, ab.y);       // beta*(v - x)
                float anow = ab.x;
                P *= anow;
                float o = fmaf(anow, pO, u * kqtt);
                o = fmaf(P, sq, o);
#pragma unroll
                for (int j = 0; j < 8; ++j) c[j] *= anow;
                if (li == (t >> 3)) c[t & 7] = u;
                if (li == 0) o_buf[obase + (size_t)(t0 + t) * HIDN] = o;
            }
            union { f16 e[8]; uint4 u4; } pkc;
#pragma unroll
            for (int j = 0; j < 8; ++j) pkc.e[j] = (f16)(c[j] * SSC);
            *(uint4*)(&c16s[vl * 40 + li * 8]) = pkc.u4;
            if (li == 0) PCs[vl] = P;
        }
        __syncthreads();
        if (ch < TLEN / SCAN_C - 1) stateUpdate();
        __syncthreads();
    }
}

// ---------------------------------------------------------------------------
// K6: LayerNorm over head dim, * g, -> f16 for output GEMM
__global__ __launch_bounds__(256) void ln_gate_kernel(
    const float* __restrict__ o_buf, const f16* __restrict__ g16,
    const float* __restrict__ lng, const float* __restrict__ lnb,
    f16* __restrict__ og16)
{
    int row = blockIdx.x;
    int h = threadIdx.x >> 5, lane = threadIdx.x & 31;
    size_t base = (size_t)row * HIDN + h * HD + lane * 4;
    float4 x = *(const float4*)(o_buf + base);
    float s  = x.x + x.y + x.z + x.w;
    float sq = x.x * x.x + x.y * x.y + x.z * x.z + x.w * x.w;
#pragma unroll
    for (int m = 1; m <= 16; m <<= 1) {
        s  += __shfl_xor(s, m);
        sq += __shfl_xor(sq, m);
    }
    float mu  = s * (1.0f / 128.0f);
    float var = sq * (1.0f / 128.0f) - mu * mu;
    float inv = 1.0f / sqrtf(var + 1e-5f);
    int d = lane * 4;
    const float* xp = (const float*)&x;
    union { f16 h4[4]; uint2 u; } pk;
#pragma unroll
    for (int j = 0; j < 4; ++j) {
        float on = (xp[j] - mu) * inv * lng[d + j] + lnb[d + j];
        pk.h4[j] = (f16)(on * (float)g16[base + j]);
    }
    *(uint2*)(og16 + base) = pk.u;
}

// ---------------------------------------------------------------------------
extern "C" void kernel_launch(void* const* d_in, const int* in_sizes, int n_in,
                              void* d_out, int out_size, void* d_ws, size_t ws_size,
                              hipStream_t stream)
{
    (void)in_sizes; (void)n_in; (void)out_size; (void)ws_size;
    const float* x   = (const float*)d_in[0];
    const float* Wq  = (const float*)d_in[1];
    const float* Wk  = (const float*)d_in[2];
    const float* Wv  = (const float*)d_in[3];
    const float* Wa  = (const float*)d_in[4];
    const float* ba  = (const float*)d_in[5];
    const float* Wb  = (const float*)d_in[6];
    const float* bb  = (const float*)d_in[7];
    const float* Wg  = (const float*)d_in[8];
    const float* Wo  = (const float*)d_in[9];
    const float* cqw = (const float*)d_in[10];
    const float* cqb = (const float*)d_in[11];
    const float* ckw = (const float*)d_in[12];
    const float* ckb = (const float*)d_in[13];
    const float* cvw = (const float*)d_in[14];
    const float* cvb = (const float*)d_in[15];
    const float* lng = (const float*)d_in[16];
    const float* lnb = (const float*)d_in[17];
    float* out = (float*)d_out;

    char* ws = (char*)d_ws;
    f16*   x16      = (f16*)(ws + 0);                 //  8,388,608 B
    f16*   WT       = (f16*)(ws + 8388608);           // 12,582,912 B
    f16*   qkvh     = (f16*)(ws + 20971520);          // 25,165,824 B
    f16*   qkv16    = (f16*)(ws + 46137344);          // 25,165,824 B (f16 q,k,v post-conv)
    float* a_buf    = (float*)(ws + 96468992);        // 16,777,216 B
    f16*   g16      = (f16*)(ws + 113246208);         //  8,388,608 B
    float* beta_buf = (float*)(ws + 121634816);       //    131,072 B
    float* o_buf    = (float*)(ws + 121765888);       // 16,777,216 B
    f16*   og16     = (f16*)(ws + 138543104);         //  8,388,608 B

    convert_x_kernel<<<dim3(4096), dim3(256), 0, stream>>>(x, x16);
    transpose_convert_kernel<<<dim3(32, 32, 6), dim3(256), 0, stream>>>(Wq, Wk, Wv, Wa, Wg, Wo, WT);
    gemm_f16<0><<<dim3(40, 32), dim3(256), 0, stream>>>(x16, WT, nullptr, qkvh, a_buf, g16, ba);
    beta_kernel<<<dim3(4096), dim3(256), 0, stream>>>(x, Wb, bb, beta_buf);
    conv_silu_kernel<<<dim3(4096, 3), dim3(256), 0, stream>>>(qkvh, cqw, cqb, ckw, ckb, cvw, cvb, qkv16);
    scan_kernel<<<dim3(8, 16), dim3(64), 0, stream>>>(
        qkv16, qkv16 + XELEMS, qkv16 + 2 * (size_t)XELEMS, a_buf, beta_buf, o_buf);
    ln_gate_kernel<<<dim3(4096), dim3(256), 0, stream>>>(o_buf, g16, lng, lnb, og16);
    gemm_f16<1><<<dim3(8, 32), dim3(256), 0, stream>>>(og16, WT + 5 * (size_t)MAT_ELEMS, out,
                                                       nullptr, nullptr, nullptr, nullptr);
}

// Round 6
// 683.065 us; speedup vs baseline: 2.5446x; 1.0652x over previous
//
#include <hip/hip_runtime.h>
#include <hip/hip_bf16.h>
#include <cstdint>
#include <cstddef>

// Problem dims (fixed)
#define BATCH 2
#define TLEN  2048
#define NHEAD 8
#define HD    128
#define HIDN  1024
#define MTOT  4096          // BATCH*TLEN
#define MAT_ELEMS 1048576   // 1024*1024
#define XELEMS 4194304      // 4096*1024

typedef _Float16 f16;
typedef _Float16 f16x8 __attribute__((ext_vector_type(8)));
typedef float    f32x4 __attribute__((ext_vector_type(4)));

__device__ __forceinline__ float sigmoidf_(float v) { return 1.0f / (1.0f + __expf(-v)); }

// ---------------------------------------------------------------------------
// K0: convert x (fp32) -> f16
__global__ __launch_bounds__(256) void convert_x_kernel(const float* __restrict__ x,
                                                        f16* __restrict__ x16)
{
    int i = (blockIdx.x * 256 + threadIdx.x) * 4;
    float4 v = *(const float4*)(x + i);
    union { f16 h[4]; uint2 u; } pk;
    pk.h[0] = (f16)v.x; pk.h[1] = (f16)v.y; pk.h[2] = (f16)v.z; pk.h[3] = (f16)v.w;
    *(uint2*)(x16 + i) = pk.u;
}

// ---------------------------------------------------------------------------
// K1: transpose-convert the six 1024x1024 weight matrices to f16 WT[mat][n][k]
__global__ __launch_bounds__(256) void transpose_convert_kernel(
    const float* __restrict__ Wq, const float* __restrict__ Wk, const float* __restrict__ Wv,
    const float* __restrict__ Wa, const float* __restrict__ Wg, const float* __restrict__ Wo,
    f16* __restrict__ WT)
{
    __shared__ float tile[32][33];
    int mat = blockIdx.z;
    const float* W = (mat == 0) ? Wq : (mat == 1) ? Wk : (mat == 2) ? Wv
                   : (mat == 3) ? Wa : (mat == 4) ? Wg : Wo;
    int k0 = blockIdx.y * 32, n0 = blockIdx.x * 32;
    int tr = threadIdx.x >> 3;
    int tc = (threadIdx.x & 7) * 4;
    float4 vin = *(const float4*)(W + (size_t)(k0 + tr) * HIDN + n0 + tc);
    tile[tr][tc + 0] = vin.x; tile[tr][tc + 1] = vin.y;
    tile[tr][tc + 2] = vin.z; tile[tr][tc + 3] = vin.w;
    __syncthreads();
    f16* dst = WT + (size_t)(mat * HIDN + n0 + tr) * HIDN + k0 + tc;
    union { f16 h[4]; uint2 u; } pk;
    pk.h[0] = (f16)tile[tc + 0][tr]; pk.h[1] = (f16)tile[tc + 1][tr];
    pk.h[2] = (f16)tile[tc + 2][tr]; pk.h[3] = (f16)tile[tc + 3][tr];
    *(uint2*)dst = pk.u;
}

// ---------------------------------------------------------------------------
// K2/K7: f16 MFMA GEMM, C = A[M,1024] @ BT[n][k]^T, 128x128 tile, BK=32.
template <int MODE>
__global__ __launch_bounds__(256) void gemm_f16(
    const f16* __restrict__ A, const f16* __restrict__ BT,
    float* __restrict__ out_f32,
    f16* __restrict__ qkv_hat, float* __restrict__ a_buf, f16* __restrict__ g16,
    const float* __restrict__ ba)
{
    __shared__ __align__(16) f16 As[128][40];
    __shared__ __align__(16) f16 Bs[128][40];
    int m0 = blockIdx.y * 128;
    int n0 = blockIdx.x * 128;
    int tid = threadIdx.x;
    int w = tid >> 6, lane = tid & 63;
    int L16 = lane & 15, quad = lane >> 4;
    int wm = (w >> 1) * 64, wn = (w & 1) * 64;

    f32x4 acc[4][4];
#pragma unroll
    for (int i = 0; i < 4; ++i)
#pragma unroll
        for (int j = 0; j < 4; ++j) acc[i][j] = (f32x4){0.f, 0.f, 0.f, 0.f};

    int ldr = tid >> 2;
    int ldc = (tid & 3) * 8;

    for (int k0 = 0; k0 < 1024; k0 += 32) {
        uint4 a0 = *(const uint4*)(A + (size_t)(m0 + ldr) * HIDN + k0 + ldc);
        uint4 a1 = *(const uint4*)(A + (size_t)(m0 + ldr + 64) * HIDN + k0 + ldc);
        uint4 b0 = *(const uint4*)(BT + (size_t)(n0 + ldr) * HIDN + k0 + ldc);
        uint4 b1 = *(const uint4*)(BT + (size_t)(n0 + ldr + 64) * HIDN + k0 + ldc);
        __syncthreads();
        *(uint4*)(&As[ldr][ldc]) = a0;
        *(uint4*)(&As[ldr + 64][ldc]) = a1;
        *(uint4*)(&Bs[ldr][ldc]) = b0;
        *(uint4*)(&Bs[ldr + 64][ldc]) = b1;
        __syncthreads();
        f16x8 af[4], bf[4];
#pragma unroll
        for (int i = 0; i < 4; ++i) {
            af[i] = *(const f16x8*)(&As[wm + i * 16 + L16][quad * 8]);
            bf[i] = *(const f16x8*)(&Bs[wn + i * 16 + L16][quad * 8]);
        }
#pragma unroll
        for (int i = 0; i < 4; ++i)
#pragma unroll
            for (int j = 0; j < 4; ++j)
                acc[i][j] = __builtin_amdgcn_mfma_f32_16x16x32_f16(af[i], bf[j], acc[i][j], 0, 0, 0);
    }

#pragma unroll
    for (int i = 0; i < 4; ++i) {
#pragma unroll
        for (int j = 0; j < 4; ++j) {
            f32x4 c = acc[i][j];
            int mbase = m0 + wm + i * 16 + quad * 4;
            int n = n0 + wn + j * 16 + L16;
            if (MODE == 1) {
#pragma unroll
                for (int r = 0; r < 4; ++r)
                    out_f32[(size_t)(mbase + r) * HIDN + n] = c[r];
            } else {
                int mat = n >> 10;
                int nn = n & 1023;
                if (mat < 3) {
#pragma unroll
                    for (int r = 0; r < 4; ++r)
                        qkv_hat[(size_t)mat * XELEMS + (size_t)(mbase + r) * HIDN + nn] = (f16)c[r];
                } else if (mat == 3) {
                    float bav = ba[nn];
#pragma unroll
                    for (int r = 0; r < 4; ++r)
                        a_buf[(size_t)(mbase + r) * HIDN + nn] = sigmoidf_(c[r] + bav);
                } else {
#pragma unroll
                    for (int r = 0; r < 4; ++r)
                        g16[(size_t)(mbase + r) * HIDN + nn] = (f16)sigmoidf_(c[r]);
                }
            }
        }
    }
}

// ---------------------------------------------------------------------------
// K3: beta = sigmoid(x @ Wb + bb), fp32 exact path.
__global__ __launch_bounds__(256) void beta_kernel(const float* __restrict__ x,
                                                   const float* __restrict__ Wb,
                                                   const float* __restrict__ bb,
                                                   float* __restrict__ beta_buf)
{
    int row = blockIdx.x;
    int h = threadIdx.x >> 5, lane = threadIdx.x & 31;
    const float* xr = x + (size_t)row * HIDN;
    float part = 0.f;
    for (int i = lane; i < HIDN; i += 32)
        part += xr[i] * Wb[i * NHEAD + h];
#pragma unroll
    for (int m = 1; m <= 16; m <<= 1) part += __shfl_xor(part, m);
    if (lane == 0)
        beta_buf[(size_t)row * NHEAD + h] = sigmoidf_(part + bb[h]);
}

// ---------------------------------------------------------------------------
// K4: causal depthwise conv (K=4) + SiLU (+ scale for k), f16 output.
__global__ __launch_bounds__(256) void conv_silu_kernel(
    const f16* __restrict__ qkv_hat,
    const float* __restrict__ cqw, const float* __restrict__ cqb,
    const float* __restrict__ ckw, const float* __restrict__ ckb,
    const float* __restrict__ cvw, const float* __restrict__ cvb,
    f16* __restrict__ qkv16)
{
    int z = blockIdx.y;
    int row = blockIdx.x;
    int tloc = row & (TLEN - 1);
    int c4 = threadIdx.x * 4;
    const f16* src = qkv_hat + (size_t)z * XELEMS;
    const float* w  = (z == 0) ? cqw : (z == 1) ? ckw : cvw;
    const float* bi = (z == 0) ? cqb : (z == 1) ? ckb : cvb;

    float xv[4][4];
#pragma unroll
    for (int j = 0; j < 4; ++j) {
        int tt = tloc - 3 + j;
        if (tt >= 0) {
            const f16* p = src + (size_t)(row - 3 + j) * HIDN + c4;
            xv[j][0] = (float)p[0]; xv[j][1] = (float)p[1];
            xv[j][2] = (float)p[2]; xv[j][3] = (float)p[3];
        } else {
            xv[j][0] = xv[j][1] = xv[j][2] = xv[j][3] = 0.f;
        }
    }
    float scale = (z == 1) ? 0.08838834764831845f : 1.0f;  // 128^-0.5 for k
    union { f16 h[4]; uint2 u; } pk;
#pragma unroll
    for (int cc = 0; cc < 4; ++cc) {
        float4 wc = *(const float4*)(w + (size_t)(c4 + cc) * 4);
        float acc = bi[c4 + cc] + wc.x * xv[0][cc] + wc.y * xv[1][cc]
                                 + wc.z * xv[2][cc] + wc.w * xv[3][cc];
        pk.h[cc] = (f16)(acc * sigmoidf_(acc) * scale);
    }
    *(uint2*)(qkv16 + (size_t)z * XELEMS + (size_t)row * HIDN + c4) = pk.u;
}

// ---------------------------------------------------------------------------
// K5: chunked delta-rule scan, v-split, wave-synchronous (single-wave blocks,
// NO __syncthreads -> prefetch loads are never drained by a barrier; they hide
// under the solve). Grid = (16 bh, 8 vsplit): the 8 blocks sharing one bh's
// k/q stream are adjacent in linear-ID mod 16 -> land on one XCD (L2 reuse).
// Solve processes 2 steps per iteration (halved DPP-chain depth); state
// update uses mfma(K^T-frag, c^T-frag) so the Sp RMW is float4-wide.
#define SCAN_C 32
#define SSC  1024.0f
#define ISSC 0.0009765625f

__global__ __launch_bounds__(64) void scan_kernel(
    const f16* __restrict__ q16, const f16* __restrict__ k16, const f16* __restrict__ v16,
    const float* __restrict__ a_buf, const float* __restrict__ beta_buf,
    float* __restrict__ o_buf)
{
    __shared__ __align__(16) float Sp[16 * 132];    // state slice [v][k], x1024
    __shared__ __align__(16) f16   Ks[32 * 136];    // K chunk [t][k]
    __shared__ __align__(16) float Gts[32 * 36];    // Gts[t][tau] = k_tau . k_t
    __shared__ __align__(16) float KQts[32 * 36];   // KQts[t][tau] = k_tau . q_t
    __shared__ __align__(16) float sk0t[32 * 20];   // [t][v] (x1024)
    __shared__ __align__(16) float sq0t[32 * 20];
    __shared__ __align__(16) float avbv[32 * 40];   // [t][2v+{a, beta*v}]
    __shared__ __align__(16) float Bts[32];
    __shared__ __align__(16) f16   c16s[16 * 40];   // [v][tau], x1024
    __shared__ __align__(16) float PCs[16];

    int bh = blockIdx.x;
    int b = bh >> 3, h = bh & 7;
    int v0 = blockIdx.y * 16;
    int lane = threadIdx.x;
    int L16 = lane & 15, quad = lane >> 4;
    int vl = lane >> 2, li = lane & 3;
    int t_av = lane >> 1, halfsel = lane & 1;
    const size_t rowbase = (size_t)(b * TLEN) * HIDN + h * HD;

    // prefetch registers for one chunk
    f16x8 kf[2][4], qf[2][4];
    float4 ar0, ar1; uint4 vr; float betr = 0.f;

    auto prefetch = [&](int t0) {
#pragma unroll
        for (int nt = 0; nt < 2; ++nt)
#pragma unroll
            for (int kk = 0; kk < 4; ++kk) {
                size_t g = rowbase + (size_t)(t0 + nt * 16 + L16) * HIDN + kk * 32 + quad * 8;
                kf[nt][kk] = *(const f16x8*)(k16 + g);
                qf[nt][kk] = *(const f16x8*)(q16 + g);
            }
        size_t ga = rowbase + (size_t)(t0 + t_av) * HIDN + v0 + halfsel * 8;
        ar0 = *(const float4*)(a_buf + ga);
        ar1 = *(const float4*)(a_buf + ga + 4);
        vr  = *(const uint4*)(v16 + ga);
        betr = beta_buf[((size_t)(b * TLEN) + t0 + t_av) * NHEAD + h];
    };

    auto stage = [&]() {
#pragma unroll
        for (int nt = 0; nt < 2; ++nt)
#pragma unroll
            for (int kk = 0; kk < 4; ++kk)
                *(f16x8*)(&Ks[(nt * 16 + L16) * 136 + kk * 32 + quad * 8]) = kf[nt][kk];
        const f16* vh = (const f16*)&vr;
        float* dst = &avbv[t_av * 40 + halfsel * 16];
        float4 w0 = {ar0.x, betr * (float)vh[0], ar0.y, betr * (float)vh[1]};
        float4 w1 = {ar0.z, betr * (float)vh[2], ar0.w, betr * (float)vh[3]};
        float4 w2 = {ar1.x, betr * (float)vh[4], ar1.y, betr * (float)vh[5]};
        float4 w3 = {ar1.z, betr * (float)vh[6], ar1.w, betr * (float)vh[7]};
        *(float4*)(dst + 0)  = w0;
        *(float4*)(dst + 4)  = w1;
        *(float4*)(dst + 8)  = w2;
        *(float4*)(dst + 12) = w3;
        if (halfsel == 0) Bts[t_av] = betr;
    };

    auto computeMM = [&]() {
        f32x4 accG[2][2], accKQ[2][2], accK[2], accQ[2];
#pragma unroll
        for (int i = 0; i < 2; ++i) {
            accK[i] = (f32x4){0, 0, 0, 0}; accQ[i] = (f32x4){0, 0, 0, 0};
#pragma unroll
            for (int j = 0; j < 2; ++j) { accG[i][j] = (f32x4){0, 0, 0, 0}; accKQ[i][j] = (f32x4){0, 0, 0, 0}; }
        }
#pragma unroll
        for (int kk = 0; kk < 4; ++kk) {
            float4 s0 = *(const float4*)(&Sp[L16 * 132 + kk * 32 + quad * 8]);
            float4 s1 = *(const float4*)(&Sp[L16 * 132 + kk * 32 + quad * 8 + 4]);
            f16x8 sf;
            sf[0] = (f16)s0.x; sf[1] = (f16)s0.y; sf[2] = (f16)s0.z; sf[3] = (f16)s0.w;
            sf[4] = (f16)s1.x; sf[5] = (f16)s1.y; sf[6] = (f16)s1.z; sf[7] = (f16)s1.w;
#pragma unroll
            for (int nt = 0; nt < 2; ++nt) {
                accK[nt] = __builtin_amdgcn_mfma_f32_16x16x32_f16(sf, kf[nt][kk], accK[nt], 0, 0, 0);
                accQ[nt] = __builtin_amdgcn_mfma_f32_16x16x32_f16(sf, qf[nt][kk], accQ[nt], 0, 0, 0);
#pragma unroll
                for (int mt = 0; mt < 2; ++mt) {
                    accG[mt][nt]  = __builtin_amdgcn_mfma_f32_16x16x32_f16(kf[mt][kk], kf[nt][kk], accG[mt][nt], 0, 0, 0);
                    accKQ[mt][nt] = __builtin_amdgcn_mfma_f32_16x16x32_f16(kf[mt][kk], qf[nt][kk], accKQ[mt][nt], 0, 0, 0);
                }
            }
        }
#pragma unroll
        for (int nt = 0; nt < 2; ++nt) {
            int t = nt * 16 + L16;
#pragma unroll
            for (int mt = 0; mt < 2; ++mt) {
                *(f32x4*)(&Gts[t * 36 + mt * 16 + quad * 4])  = accG[mt][nt];
                *(f32x4*)(&KQts[t * 36 + mt * 16 + quad * 4]) = accKQ[mt][nt];
            }
            *(f32x4*)(&sk0t[t * 20 + quad * 4]) = accK[nt];
            *(f32x4*)(&sq0t[t * 20 + quad * 4]) = accQ[nt];
        }
    };

    prefetch(0);
    for (int i = lane; i < 16 * 132; i += 64) Sp[i] = 0.f;

    const size_t obase = rowbase + v0 + vl;
    const int NCH = TLEN / SCAN_C;

    for (int ch = 0; ch < NCH; ++ch) {
        int t0 = ch * SCAN_C;
        stage();
        computeMM();

        // gather K^T A-fragments for the state update (off the critical path)
        f16x8 bu[8];
#pragma unroll
        for (int kt = 0; kt < 8; ++kt)
#pragma unroll
            for (int j = 0; j < 8; ++j)
                bu[kt][j] = Ks[(quad * 8 + j) * 136 + kt * 16 + L16];

        if (ch < NCH - 1) prefetch(t0 + SCAN_C);   // hides under the solve (no barrier!)

        // ---- triangular solve, 2 steps per iteration, c[] in registers ----
        {
            float c[8];
#pragma unroll
            for (int j = 0; j < 8; ++j) c[j] = 0.f;
            float P = 1.f;
#pragma unroll
            for (int t = 0; t < SCAN_C; t += 2) {
                float4 g0 = *(const float4*)(&Gts[t * 36 + li * 8]);
                float4 g1 = *(const float4*)(&Gts[t * 36 + li * 8 + 4]);
                float4 G0 = *(const float4*)(&Gts[(t + 1) * 36 + li * 8]);
                float4 G1 = *(const float4*)(&Gts[(t + 1) * 36 + li * 8 + 4]);
                float4 h0 = *(const float4*)(&KQts[t * 36 + li * 8]);
                float4 h1 = *(const float4*)(&KQts[t * 36 + li * 8 + 4]);
                float4 H0 = *(const float4*)(&KQts[(t + 1) * 36 + li * 8]);
                float4 H1 = *(const float4*)(&KQts[(t + 1) * 36 + li * 8 + 4]);
                float2 ab0 = *(const float2*)(&avbv[t * 40 + vl * 2]);
                float2 ab1 = *(const float2*)(&avbv[(t + 1) * 40 + vl * 2]);
                float bt0 = Bts[t], bt1 = Bts[t + 1];
                float sk0 = sk0t[t * 20 + vl] * ISSC;
                float sk1 = sk0t[(t + 1) * 20 + vl] * ISSC;
                float sq0 = sq0t[t * 20 + vl] * ISSC;
                float sq1 = sq0t[(t + 1) * 20 + vl] * ISSC;
                float kq00 = KQts[t * 36 + t];
                float kq11 = KQts[(t + 1) * 36 + (t + 1)];
                float g01  = Gts[(t + 1) * 36 + t];
                float kq01 = KQts[(t + 1) * 36 + t];

                float pG  = (fmaf(c[0], g0.x, c[1] * g0.y) + fmaf(c[2], g0.z, c[3] * g0.w))
                          + (fmaf(c[4], g1.x, c[5] * g1.y) + fmaf(c[6], g1.z, c[7] * g1.w));
                float pG1 = (fmaf(c[0], G0.x, c[1] * G0.y) + fmaf(c[2], G0.z, c[3] * G0.w))
                          + (fmaf(c[4], G1.x, c[5] * G1.y) + fmaf(c[6], G1.z, c[7] * G1.w));
                float pO  = (fmaf(c[0], h0.x, c[1] * h0.y) + fmaf(c[2], h0.z, c[3] * h0.w))
                          + (fmaf(c[4], h1.x, c[5] * h1.y) + fmaf(c[6], h1.z, c[7] * h1.w));
                float pO1 = (fmaf(c[0], H0.x, c[1] * H0.y) + fmaf(c[2], H0.z, c[3] * H0.w))
                          + (fmaf(c[4], H1.x, c[5] * H1.y) + fmaf(c[6], H1.z, c[7] * H1.w));
                int tmp;
                tmp = __builtin_amdgcn_update_dpp(0, __float_as_int(pG),  0xB1, 0xF, 0xF, true); pG  += __int_as_float(tmp);
                tmp = __builtin_amdgcn_update_dpp(0, __float_as_int(pG1), 0xB1, 0xF, 0xF, true); pG1 += __int_as_float(tmp);
                tmp = __builtin_amdgcn_update_dpp(0, __float_as_int(pO),  0xB1, 0xF, 0xF, true); pO  += __int_as_float(tmp);
                tmp = __builtin_amdgcn_update_dpp(0, __float_as_int(pO1), 0xB1, 0xF, 0xF, true); pO1 += __int_as_float(tmp);
                tmp = __builtin_amdgcn_update_dpp(0, __float_as_int(pG),  0x4E, 0xF, 0xF, true); pG  += __int_as_float(tmp);
                tmp = __builtin_amdgcn_update_dpp(0, __float_as_int(pG1), 0x4E, 0xF, 0xF, true); pG1 += __int_as_float(tmp);
                tmp = __builtin_amdgcn_update_dpp(0, __float_as_int(pO),  0x4E, 0xF, 0xF, true); pO  += __int_as_float(tmp);
                tmp = __builtin_amdgcn_update_dpp(0, __float_as_int(pO1), 0x4E, 0xF, 0xF, true); pO1 += __int_as_float(tmp);

                float a0 = ab0.x, a1 = ab1.x;
                // step t
                float x0 = fmaf(P, sk0, pG);
                float u0 = fmaf(-bt0, x0, ab0.y);
                float P0 = P * a0;
                float o0 = fmaf(a0, pO, u0 * kq00);
                o0 = fmaf(P0, sq0, o0);
                // step t+1 (cross-terms via u0 explicitly)
                float accG = fmaf(a0, pG1, u0 * g01);
                float x1 = fmaf(P0, sk1, accG);
                float u1 = fmaf(-bt1, x1, ab1.y);
                float P1 = P0 * a1;
                float accO = fmaf(a0, pO1, u0 * kq01);
                float o1 = fmaf(a1, accO, u1 * kq11);
                o1 = fmaf(P1, sq1, o1);

                float aa = a0 * a1;
#pragma unroll
                for (int j = 0; j < 8; ++j) c[j] *= aa;
                if (li == (t >> 3)) { c[t & 7] = u0 * a1; c[(t + 1) & 7] = u1; }
                P = P1;
                if (li == 0) {
                    o_buf[obase + (size_t)(t0 + t) * HIDN]     = o0;
                    o_buf[obase + (size_t)(t0 + t + 1) * HIDN] = o1;
                }
            }
            union { f16 e[8]; uint4 u4; } pkc;
#pragma unroll
            for (int j = 0; j < 8; ++j) pkc.e[j] = (f16)(c[j] * SSC);
            *(uint4*)(&c16s[vl * 40 + li * 8]) = pkc.u4;
            if (li == 0) PCs[vl] = P;
        }

        // ---- state update: D^T = K^T @ c^T -> float4 RMW on Sp[v][k] ----
        if (ch < NCH - 1) {
            f16x8 ca = *(const f16x8*)(&c16s[L16 * 40 + quad * 8]);
            float pc = PCs[L16];
#pragma unroll
            for (int kt = 0; kt < 8; ++kt) {
                f32x4 d = __builtin_amdgcn_mfma_f32_16x16x32_f16(bu[kt], ca, (f32x4){0, 0, 0, 0}, 0, 0, 0);
                int idx = L16 * 132 + kt * 16 + quad * 4;
                float4 s = *(const float4*)(&Sp[idx]);
                s.x = fmaf(pc, s.x, d[0]);
                s.y = fmaf(pc, s.y, d[1]);
                s.z = fmaf(pc, s.z, d[2]);
                s.w = fmaf(pc, s.w, d[3]);
                *(float4*)(&Sp[idx]) = s;
            }
        }
    }
}

// ---------------------------------------------------------------------------
// K6: LayerNorm over head dim, * g, -> f16 for output GEMM
__global__ __launch_bounds__(256) void ln_gate_kernel(
    const float* __restrict__ o_buf, const f16* __restrict__ g16,
    const float* __restrict__ lng, const float* __restrict__ lnb,
    f16* __restrict__ og16)
{
    int row = blockIdx.x;
    int h = threadIdx.x >> 5, lane = threadIdx.x & 31;
    size_t base = (size_t)row * HIDN + h * HD + lane * 4;
    float4 x = *(const float4*)(o_buf + base);
    float s  = x.x + x.y + x.z + x.w;
    float sq = x.x * x.x + x.y * x.y + x.z * x.z + x.w * x.w;
#pragma unroll
    for (int m = 1; m <= 16; m <<= 1) {
        s  += __shfl_xor(s, m);
        sq += __shfl_xor(sq, m);
    }
    float mu  = s * (1.0f / 128.0f);
    float var = sq * (1.0f / 128.0f) - mu * mu;
    float inv = 1.0f / sqrtf(var + 1e-5f);
    int d = lane * 4;
    const float* xp = (const float*)&x;
    union { f16 h4[4]; uint2 u; } pk;
#pragma unroll
    for (int j = 0; j < 4; ++j) {
        float on = (xp[j] - mu) * inv * lng[d + j] + lnb[d + j];
        pk.h4[j] = (f16)(on * (float)g16[base + j]);
    }
    *(uint2*)(og16 + base) = pk.u;
}

// ---------------------------------------------------------------------------
extern "C" void kernel_launch(void* const* d_in, const int* in_sizes, int n_in,
                              void* d_out, int out_size, void* d_ws, size_t ws_size,
                              hipStream_t stream)
{
    (void)in_sizes; (void)n_in; (void)out_size; (void)ws_size;
    const float* x   = (const float*)d_in[0];
    const float* Wq  = (const float*)d_in[1];
    const float* Wk  = (const float*)d_in[2];
    const float* Wv  = (const float*)d_in[3];
    const float* Wa  = (const float*)d_in[4];
    const float* ba  = (const float*)d_in[5];
    const float* Wb  = (const float*)d_in[6];
    const float* bb  = (const float*)d_in[7];
    const float* Wg  = (const float*)d_in[8];
    const float* Wo  = (const float*)d_in[9];
    const float* cqw = (const float*)d_in[10];
    const float* cqb = (const float*)d_in[11];
    const float* ckw = (const float*)d_in[12];
    const float* ckb = (const float*)d_in[13];
    const float* cvw = (const float*)d_in[14];
    const float* cvb = (const float*)d_in[15];
    const float* lng = (const float*)d_in[16];
    const float* lnb = (const float*)d_in[17];
    float* out = (float*)d_out;

    char* ws = (char*)d_ws;
    f16*   x16      = (f16*)(ws + 0);                 //  8,388,608 B
    f16*   WT       = (f16*)(ws + 8388608);           // 12,582,912 B
    f16*   qkvh     = (f16*)(ws + 20971520);          // 25,165,824 B
    f16*   qkv16    = (f16*)(ws + 46137344);          // 25,165,824 B (f16 q,k,v post-conv)
    float* a_buf    = (float*)(ws + 96468992);        // 16,777,216 B
    f16*   g16      = (f16*)(ws + 113246208);         //  8,388,608 B
    float* beta_buf = (float*)(ws + 121634816);       //    131,072 B
    float* o_buf    = (float*)(ws + 121765888);       // 16,777,216 B
    f16*   og16     = (f16*)(ws + 138543104);         //  8,388,608 B

    convert_x_kernel<<<dim3(4096), dim3(256), 0, stream>>>(x, x16);
    transpose_convert_kernel<<<dim3(32, 32, 6), dim3(256), 0, stream>>>(Wq, Wk, Wv, Wa, Wg, Wo, WT);
    gemm_f16<0><<<dim3(40, 32), dim3(256), 0, stream>>>(x16, WT, nullptr, qkvh, a_buf, g16, ba);
    beta_kernel<<<dim3(4096), dim3(256), 0, stream>>>(x, Wb, bb, beta_buf);
    conv_silu_kernel<<<dim3(4096, 3), dim3(256), 0, stream>>>(qkvh, cqw, cqb, ckw, ckb, cvw, cvb, qkv16);
    scan_kernel<<<dim3(16, 8), dim3(64), 0, stream>>>(
        qkv16, qkv16 + XELEMS, qkv16 + 2 * (size_t)XELEMS, a_buf, beta_buf, o_buf);
    ln_gate_kernel<<<dim3(4096), dim3(256), 0, stream>>>(o_buf, g16, lng, lnb, og16);
    gemm_f16<1><<<dim3(8, 32), dim3(256), 0, stream>>>(og16, WT + 5 * (size_t)MAT_ELEMS, out,
                                                       nullptr, nullptr, nullptr, nullptr);
}

// Round 7
// 616.949 us; speedup vs baseline: 2.8173x; 1.1072x over previous
//
#include <hip/hip_runtime.h>
#include <hip/hip_bf16.h>
#include <cstdint>
#include <cstddef>

// Problem dims (fixed)
#define BATCH 2
#define TLEN  2048
#define NHEAD 8
#define HD    128
#define HIDN  1024
#define MTOT  4096          // BATCH*TLEN
#define MAT_ELEMS 1048576   // 1024*1024
#define XELEMS 4194304      // 4096*1024

typedef _Float16 f16;
typedef _Float16 f16x2 __attribute__((ext_vector_type(2)));
typedef _Float16 f16x8 __attribute__((ext_vector_type(8)));
typedef float    f32x4 __attribute__((ext_vector_type(4)));

__device__ __forceinline__ float sigmoidf_(float v) { return 1.0f / (1.0f + __expf(-v)); }

// f16x2 dot with f32 accumulate: v_dot2_f32_f16 (exact products, f32 accum)
__device__ __forceinline__ float fdot2_(f16x2 a, f16x2 b, float c)
{
#if __has_builtin(__builtin_amdgcn_fdot2)
    return __builtin_amdgcn_fdot2(a, b, c, false);
#else
    return fmaf((float)a.x, (float)b.x, fmaf((float)a.y, (float)b.y, c));
#endif
}

// ---------------------------------------------------------------------------
// K0: convert x (fp32) -> f16
__global__ __launch_bounds__(256) void convert_x_kernel(const float* __restrict__ x,
                                                        f16* __restrict__ x16)
{
    int i = (blockIdx.x * 256 + threadIdx.x) * 4;
    float4 v = *(const float4*)(x + i);
    union { f16 h[4]; uint2 u; } pk;
    pk.h[0] = (f16)v.x; pk.h[1] = (f16)v.y; pk.h[2] = (f16)v.z; pk.h[3] = (f16)v.w;
    *(uint2*)(x16 + i) = pk.u;
}

// ---------------------------------------------------------------------------
// K1: transpose-convert the six 1024x1024 weight matrices to f16 WT[mat][n][k]
__global__ __launch_bounds__(256) void transpose_convert_kernel(
    const float* __restrict__ Wq, const float* __restrict__ Wk, const float* __restrict__ Wv,
    const float* __restrict__ Wa, const float* __restrict__ Wg, const float* __restrict__ Wo,
    f16* __restrict__ WT)
{
    __shared__ float tile[32][33];
    int mat = blockIdx.z;
    const float* W = (mat == 0) ? Wq : (mat == 1) ? Wk : (mat == 2) ? Wv
                   : (mat == 3) ? Wa : (mat == 4) ? Wg : Wo;
    int k0 = blockIdx.y * 32, n0 = blockIdx.x * 32;
    int tr = threadIdx.x >> 3;
    int tc = (threadIdx.x & 7) * 4;
    float4 vin = *(const float4*)(W + (size_t)(k0 + tr) * HIDN + n0 + tc);
    tile[tr][tc + 0] = vin.x; tile[tr][tc + 1] = vin.y;
    tile[tr][tc + 2] = vin.z; tile[tr][tc + 3] = vin.w;
    __syncthreads();
    f16* dst = WT + (size_t)(mat * HIDN + n0 + tr) * HIDN + k0 + tc;
    union { f16 h[4]; uint2 u; } pk;
    pk.h[0] = (f16)tile[tc + 0][tr]; pk.h[1] = (f16)tile[tc + 1][tr];
    pk.h[2] = (f16)tile[tc + 2][tr]; pk.h[3] = (f16)tile[tc + 3][tr];
    *(uint2*)dst = pk.u;
}

// ---------------------------------------------------------------------------
// K2/K7: f16 MFMA GEMM, C = A[M,1024] @ BT[n][k]^T, 128x128 tile, BK=32.
template <int MODE>
__global__ __launch_bounds__(256) void gemm_f16(
    const f16* __restrict__ A, const f16* __restrict__ BT,
    float* __restrict__ out_f32,
    f16* __restrict__ qkv_hat, float* __restrict__ a_buf, f16* __restrict__ g16,
    const float* __restrict__ ba)
{
    __shared__ __align__(16) f16 As[128][40];
    __shared__ __align__(16) f16 Bs[128][40];
    int m0 = blockIdx.y * 128;
    int n0 = blockIdx.x * 128;
    int tid = threadIdx.x;
    int w = tid >> 6, lane = tid & 63;
    int L16 = lane & 15, quad = lane >> 4;
    int wm = (w >> 1) * 64, wn = (w & 1) * 64;

    f32x4 acc[4][4];
#pragma unroll
    for (int i = 0; i < 4; ++i)
#pragma unroll
        for (int j = 0; j < 4; ++j) acc[i][j] = (f32x4){0.f, 0.f, 0.f, 0.f};

    int ldr = tid >> 2;
    int ldc = (tid & 3) * 8;

    for (int k0 = 0; k0 < 1024; k0 += 32) {
        uint4 a0 = *(const uint4*)(A + (size_t)(m0 + ldr) * HIDN + k0 + ldc);
        uint4 a1 = *(const uint4*)(A + (size_t)(m0 + ldr + 64) * HIDN + k0 + ldc);
        uint4 b0 = *(const uint4*)(BT + (size_t)(n0 + ldr) * HIDN + k0 + ldc);
        uint4 b1 = *(const uint4*)(BT + (size_t)(n0 + ldr + 64) * HIDN + k0 + ldc);
        __syncthreads();
        *(uint4*)(&As[ldr][ldc]) = a0;
        *(uint4*)(&As[ldr + 64][ldc]) = a1;
        *(uint4*)(&Bs[ldr][ldc]) = b0;
        *(uint4*)(&Bs[ldr + 64][ldc]) = b1;
        __syncthreads();
        f16x8 af[4], bf[4];
#pragma unroll
        for (int i = 0; i < 4; ++i) {
            af[i] = *(const f16x8*)(&As[wm + i * 16 + L16][quad * 8]);
            bf[i] = *(const f16x8*)(&Bs[wn + i * 16 + L16][quad * 8]);
        }
#pragma unroll
        for (int i = 0; i < 4; ++i)
#pragma unroll
            for (int j = 0; j < 4; ++j)
                acc[i][j] = __builtin_amdgcn_mfma_f32_16x16x32_f16(af[i], bf[j], acc[i][j], 0, 0, 0);
    }

#pragma unroll
    for (int i = 0; i < 4; ++i) {
#pragma unroll
        for (int j = 0; j < 4; ++j) {
            f32x4 c = acc[i][j];
            int mbase = m0 + wm + i * 16 + quad * 4;
            int n = n0 + wn + j * 16 + L16;
            if (MODE == 1) {
#pragma unroll
                for (int r = 0; r < 4; ++r)
                    out_f32[(size_t)(mbase + r) * HIDN + n] = c[r];
            } else {
                int mat = n >> 10;
                int nn = n & 1023;
                if (mat < 3) {
#pragma unroll
                    for (int r = 0; r < 4; ++r)
                        qkv_hat[(size_t)mat * XELEMS + (size_t)(mbase + r) * HIDN + nn] = (f16)c[r];
                } else if (mat == 3) {
                    float bav = ba[nn];
#pragma unroll
                    for (int r = 0; r < 4; ++r)
                        a_buf[(size_t)(mbase + r) * HIDN + nn] = sigmoidf_(c[r] + bav);
                } else {
#pragma unroll
                    for (int r = 0; r < 4; ++r)
                        g16[(size_t)(mbase + r) * HIDN + nn] = (f16)sigmoidf_(c[r]);
                }
            }
        }
    }
}

// ---------------------------------------------------------------------------
// K3: beta = sigmoid(x @ Wb + bb), fp32 exact path.
__global__ __launch_bounds__(256) void beta_kernel(const float* __restrict__ x,
                                                   const float* __restrict__ Wb,
                                                   const float* __restrict__ bb,
                                                   float* __restrict__ beta_buf)
{
    int row = blockIdx.x;
    int h = threadIdx.x >> 5, lane = threadIdx.x & 31;
    const float* xr = x + (size_t)row * HIDN;
    float part = 0.f;
    for (int i = lane; i < HIDN; i += 32)
        part += xr[i] * Wb[i * NHEAD + h];
#pragma unroll
    for (int m = 1; m <= 16; m <<= 1) part += __shfl_xor(part, m);
    if (lane == 0)
        beta_buf[(size_t)row * NHEAD + h] = sigmoidf_(part + bb[h]);
}

// ---------------------------------------------------------------------------
// K4: causal depthwise conv (K=4) + SiLU (+ scale for k), f16 output.
__global__ __launch_bounds__(256) void conv_silu_kernel(
    const f16* __restrict__ qkv_hat,
    const float* __restrict__ cqw, const float* __restrict__ cqb,
    const float* __restrict__ ckw, const float* __restrict__ ckb,
    const float* __restrict__ cvw, const float* __restrict__ cvb,
    f16* __restrict__ qkv16)
{
    int z = blockIdx.y;
    int row = blockIdx.x;
    int tloc = row & (TLEN - 1);
    int c4 = threadIdx.x * 4;
    const f16* src = qkv_hat + (size_t)z * XELEMS;
    const float* w  = (z == 0) ? cqw : (z == 1) ? ckw : cvw;
    const float* bi = (z == 0) ? cqb : (z == 1) ? ckb : cvb;

    float xv[4][4];
#pragma unroll
    for (int j = 0; j < 4; ++j) {
        int tt = tloc - 3 + j;
        if (tt >= 0) {
            const f16* p = src + (size_t)(row - 3 + j) * HIDN + c4;
            xv[j][0] = (float)p[0]; xv[j][1] = (float)p[1];
            xv[j][2] = (float)p[2]; xv[j][3] = (float)p[3];
        } else {
            xv[j][0] = xv[j][1] = xv[j][2] = xv[j][3] = 0.f;
        }
    }
    float scale = (z == 1) ? 0.08838834764831845f : 1.0f;  // 128^-0.5 for k
    union { f16 h[4]; uint2 u; } pk;
#pragma unroll
    for (int cc = 0; cc < 4; ++cc) {
        float4 wc = *(const float4*)(w + (size_t)(c4 + cc) * 4);
        float acc = bi[c4 + cc] + wc.x * xv[0][cc] + wc.y * xv[1][cc]
                                 + wc.z * xv[2][cc] + wc.w * xv[3][cc];
        pk.h[cc] = (f16)(acc * sigmoidf_(acc) * scale);
    }
    *(uint2*)(qkv16 + (size_t)z * XELEMS + (size_t)row * HIDN + c4) = pk.u;
}

// ---------------------------------------------------------------------------
// K5: chunked delta-rule scan, v-split, wave-synchronous. f16-packed solve:
// G/KQ stored f16 (lane row-fragment = one b128), c kept as 4x f16x2 in regs,
// dots via v_dot2_f32_f16 (exact f16 products, f32 accumulate), decay via
// v_pk_mul_f16. Per-v scalars re-laid-out for vector loads: sk/sq [v][t]
// float2, a/beta-v [v][2t] float4, beta float2. f16 shadow state Sp16
// (written in update) feeds computeMM fragments directly.
#define SCAN_C 32
#define SSC  1024.0f
#define ISSC 0.0009765625f

__global__ __launch_bounds__(64) void scan_kernel(
    const f16* __restrict__ q16, const f16* __restrict__ k16, const f16* __restrict__ v16,
    const float* __restrict__ a_buf, const float* __restrict__ beta_buf,
    float* __restrict__ o_buf)
{
    __shared__ __align__(16) float Sp[16 * 132];    // fp32 master state, x1024
    __shared__ __align__(16) f16   Sp16[16 * 136];  // f16 shadow for MM frags
    __shared__ __align__(16) f16   Ks[32 * 136];    // K chunk [t][k]
    __shared__ __align__(16) f16   Gf[32 * 40];     // G[t][tau] f16
    __shared__ __align__(16) f16   Qf[32 * 40];     // KQ[t][tau] f16
    __shared__ __align__(16) float skv[16 * 34];    // [v][t] (x1024)
    __shared__ __align__(16) float sqv[16 * 34];    // [v][t] (x1024)
    __shared__ __align__(16) float avb[16 * 68];    // [v][2t + {a, beta*v}]
    __shared__ __align__(16) float Bts[32];
    __shared__ __align__(16) f16   c16s[16 * 40];   // [v][tau], x1024
    __shared__ __align__(16) float PCs[16];

    int bh = blockIdx.x;
    int b = bh >> 3, h = bh & 7;
    int v0 = blockIdx.y * 16;
    int lane = threadIdx.x;
    int L16 = lane & 15, quad = lane >> 4;
    int vl = lane >> 2, li = lane & 3;
    int t_av = lane >> 1, halfsel = lane & 1;
    const size_t rowbase = (size_t)(b * TLEN) * HIDN + h * HD;

    // prefetch registers for one chunk
    f16x8 kf[2][4], qf[2][4];
    float4 ar0, ar1; uint4 vr; float betr = 0.f;

    auto prefetch = [&](int t0) {
#pragma unroll
        for (int nt = 0; nt < 2; ++nt)
#pragma unroll
            for (int kk = 0; kk < 4; ++kk) {
                size_t g = rowbase + (size_t)(t0 + nt * 16 + L16) * HIDN + kk * 32 + quad * 8;
                kf[nt][kk] = *(const f16x8*)(k16 + g);
                qf[nt][kk] = *(const f16x8*)(q16 + g);
            }
        size_t ga = rowbase + (size_t)(t0 + t_av) * HIDN + v0 + halfsel * 8;
        ar0 = *(const float4*)(a_buf + ga);
        ar1 = *(const float4*)(a_buf + ga + 4);
        vr  = *(const uint4*)(v16 + ga);
        betr = beta_buf[((size_t)(b * TLEN) + t0 + t_av) * NHEAD + h];
    };

    auto stage = [&]() {
#pragma unroll
        for (int nt = 0; nt < 2; ++nt)
#pragma unroll
            for (int kk = 0; kk < 4; ++kk)
                *(f16x8*)(&Ks[(nt * 16 + L16) * 136 + kk * 32 + quad * 8]) = kf[nt][kk];
        const f16* vh = (const f16*)&vr;
        const float* aa0 = (const float*)&ar0;
        const float* aa1 = (const float*)&ar1;
#pragma unroll
        for (int e = 0; e < 4; ++e) {
            float2 w; w.x = aa0[e]; w.y = betr * (float)vh[e];
            *(float2*)(&avb[(halfsel * 8 + e) * 68 + 2 * t_av]) = w;
        }
#pragma unroll
        for (int e = 0; e < 4; ++e) {
            float2 w; w.x = aa1[e]; w.y = betr * (float)vh[4 + e];
            *(float2*)(&avb[(halfsel * 8 + 4 + e) * 68 + 2 * t_av]) = w;
        }
        if (halfsel == 0) Bts[t_av] = betr;
    };

    auto computeMM = [&]() {
        f32x4 accG[2][2], accKQ[2][2], accK[2], accQ[2];
#pragma unroll
        for (int i = 0; i < 2; ++i) {
            accK[i] = (f32x4){0, 0, 0, 0}; accQ[i] = (f32x4){0, 0, 0, 0};
#pragma unroll
            for (int j = 0; j < 2; ++j) { accG[i][j] = (f32x4){0, 0, 0, 0}; accKQ[i][j] = (f32x4){0, 0, 0, 0}; }
        }
#pragma unroll
        for (int kk = 0; kk < 4; ++kk) {
            f16x8 sf = *(const f16x8*)(&Sp16[L16 * 136 + kk * 32 + quad * 8]);
#pragma unroll
            for (int nt = 0; nt < 2; ++nt) {
                accK[nt] = __builtin_amdgcn_mfma_f32_16x16x32_f16(sf, kf[nt][kk], accK[nt], 0, 0, 0);
                accQ[nt] = __builtin_amdgcn_mfma_f32_16x16x32_f16(sf, qf[nt][kk], accQ[nt], 0, 0, 0);
#pragma unroll
                for (int mt = 0; mt < 2; ++mt) {
                    accG[mt][nt]  = __builtin_amdgcn_mfma_f32_16x16x32_f16(kf[mt][kk], kf[nt][kk], accG[mt][nt], 0, 0, 0);
                    accKQ[mt][nt] = __builtin_amdgcn_mfma_f32_16x16x32_f16(kf[mt][kk], qf[nt][kk], accKQ[mt][nt], 0, 0, 0);
                }
            }
        }
#pragma unroll
        for (int nt = 0; nt < 2; ++nt) {
            int t = nt * 16 + L16;
#pragma unroll
            for (int mt = 0; mt < 2; ++mt) {
                union { f16 e[4]; uint2 u2; } pg, pq;
#pragma unroll
                for (int r = 0; r < 4; ++r) {
                    pg.e[r] = (f16)accG[mt][nt][r];
                    pq.e[r] = (f16)accKQ[mt][nt][r];
                }
                *(uint2*)(&Gf[t * 40 + mt * 16 + quad * 4]) = pg.u2;
                *(uint2*)(&Qf[t * 40 + mt * 16 + quad * 4]) = pq.u2;
            }
#pragma unroll
            for (int r = 0; r < 4; ++r) {
                skv[(quad * 4 + r) * 34 + t] = accK[nt][r];
                sqv[(quad * 4 + r) * 34 + t] = accQ[nt][r];
            }
        }
    };

    prefetch(0);
    for (int i = lane; i < 16 * 132; i += 64) Sp[i] = 0.f;
    for (int i = lane; i < 16 * 136; i += 64) Sp16[i] = (f16)0.f;

    const size_t obase = rowbase + v0 + vl;
    const int NCH = TLEN / SCAN_C;

    for (int ch = 0; ch < NCH; ++ch) {
        int t0 = ch * SCAN_C;
        stage();
        computeMM();

        // gather K^T A-fragments for the state update (off the critical path)
        f16x8 bu[8];
#pragma unroll
        for (int kt = 0; kt < 8; ++kt)
#pragma unroll
            for (int j = 0; j < 8; ++j)
                bu[kt][j] = Ks[(quad * 8 + j) * 136 + kt * 16 + L16];

        if (ch < NCH - 1) prefetch(t0 + SCAN_C);   // hides under the solve (no barrier)

        // ---- triangular solve, 2 steps/iter, packed f16 c + fdot2 ----
        {
            f16x2 c0, c1, c2, c3;
            c0.x = (f16)0.f; c0.y = (f16)0.f; c1 = c0; c2 = c0; c3 = c0;
            float P = 1.f;
            union RowU { uint4 u4; f16x2 p[4]; };
#pragma unroll
            for (int t = 0; t < SCAN_C; t += 2) {
                RowU g0u, g1u, h0u, h1u;
                g0u.u4 = *(const uint4*)(&Gf[t * 40 + li * 8]);
                g1u.u4 = *(const uint4*)(&Gf[(t + 1) * 40 + li * 8]);
                h0u.u4 = *(const uint4*)(&Qf[t * 40 + li * 8]);
                h1u.u4 = *(const uint4*)(&Qf[(t + 1) * 40 + li * 8]);
                float2 skp = *(const float2*)(&skv[vl * 34 + t]);
                float2 sqp = *(const float2*)(&sqv[vl * 34 + t]);
                float4 ab4 = *(const float4*)(&avb[vl * 68 + 2 * t]);
                float2 btp = *(const float2*)(&Bts[t]);
                float kq00 = (float)Qf[t * 40 + t];
                f16x2 dq  = *(const f16x2*)(&Qf[(t + 1) * 40 + t]);   // {kq01, kq11}
                float g01 = (float)Gf[(t + 1) * 40 + t];

                float pG  = fdot2_(c0, g0u.p[0], fdot2_(c1, g0u.p[1], 0.f))
                          + fdot2_(c2, g0u.p[2], fdot2_(c3, g0u.p[3], 0.f));
                float pG1 = fdot2_(c0, g1u.p[0], fdot2_(c1, g1u.p[1], 0.f))
                          + fdot2_(c2, g1u.p[2], fdot2_(c3, g1u.p[3], 0.f));
                float pO  = fdot2_(c0, h0u.p[0], fdot2_(c1, h0u.p[1], 0.f))
                          + fdot2_(c2, h0u.p[2], fdot2_(c3, h0u.p[3], 0.f));
                float pO1 = fdot2_(c0, h1u.p[0], fdot2_(c1, h1u.p[1], 0.f))
                          + fdot2_(c2, h1u.p[2], fdot2_(c3, h1u.p[3], 0.f));
                int tmp;
                tmp = __builtin_amdgcn_update_dpp(0, __float_as_int(pG),  0xB1, 0xF, 0xF, true); pG  += __int_as_float(tmp);
                tmp = __builtin_amdgcn_update_dpp(0, __float_as_int(pG1), 0xB1, 0xF, 0xF, true); pG1 += __int_as_float(tmp);
                tmp = __builtin_amdgcn_update_dpp(0, __float_as_int(pO),  0xB1, 0xF, 0xF, true); pO  += __int_as_float(tmp);
                tmp = __builtin_amdgcn_update_dpp(0, __float_as_int(pO1), 0xB1, 0xF, 0xF, true); pO1 += __int_as_float(tmp);
                tmp = __builtin_amdgcn_update_dpp(0, __float_as_int(pG),  0x4E, 0xF, 0xF, true); pG  += __int_as_float(tmp);
                tmp = __builtin_amdgcn_update_dpp(0, __float_as_int(pG1), 0x4E, 0xF, 0xF, true); pG1 += __int_as_float(tmp);
                tmp = __builtin_amdgcn_update_dpp(0, __float_as_int(pO),  0x4E, 0xF, 0xF, true); pO  += __int_as_float(tmp);
                tmp = __builtin_amdgcn_update_dpp(0, __float_as_int(pO1), 0x4E, 0xF, 0xF, true); pO1 += __int_as_float(tmp);

                float a0 = ab4.x, bv0 = ab4.y, a1 = ab4.z, bv1 = ab4.w;
                float bt0 = btp.x, bt1 = btp.y;
                float sk0 = skp.x * ISSC, sk1 = skp.y * ISSC;
                float sq0 = sqp.x * ISSC, sq1 = sqp.y * ISSC;
                float kq01 = (float)dq.x, kq11 = (float)dq.y;

                // step t
                float x0 = fmaf(P, sk0, pG);
                float u0 = fmaf(-bt0, x0, bv0);
                float P0 = P * a0;
                float o0 = fmaf(a0, pO, u0 * kq00);
                o0 = fmaf(P0, sq0, o0);
                // step t+1 (cross-terms via u0 explicitly)
                float accGv = fmaf(a0, pG1, u0 * g01);
                float x1 = fmaf(P0, sk1, accGv);
                float u1 = fmaf(-bt1, x1, bv1);
                float P1 = P0 * a1;
                float accOv = fmaf(a0, pO1, u0 * kq01);
                float o1 = fmaf(a1, accOv, u1 * kq11);
                o1 = fmaf(P1, sq1, o1);

                float aa = a0 * a1;
                f16 aah = (f16)aa;
                f16x2 aa2; aa2.x = aah; aa2.y = aah;
                c0 *= aa2; c1 *= aa2; c2 *= aa2; c3 *= aa2;
                if (li == (t >> 3)) {
                    f16x2 un; un.x = (f16)(u0 * a1); un.y = (f16)u1;
                    int p = (t & 7) >> 1;
                    if (p == 0) c0 = un; else if (p == 1) c1 = un;
                    else if (p == 2) c2 = un; else c3 = un;
                }
                P = P1;
                if (li == 0) {
                    o_buf[obase + (size_t)(t0 + t) * HIDN]     = o0;
                    o_buf[obase + (size_t)(t0 + t + 1) * HIDN] = o1;
                }
            }
            f16 s16 = (f16)SSC;
            f16x2 ss2; ss2.x = s16; ss2.y = s16;
            union { f16x2 p[4]; uint4 u4; } pc;
            pc.p[0] = c0 * ss2; pc.p[1] = c1 * ss2; pc.p[2] = c2 * ss2; pc.p[3] = c3 * ss2;
            *(uint4*)(&c16s[vl * 40 + li * 8]) = pc.u4;
            if (li == 0) PCs[vl] = P;
        }

        // ---- state update: D^T = K^T @ c^T -> float4 RMW + f16 shadow ----
        if (ch < NCH - 1) {
            f16x8 ca = *(const f16x8*)(&c16s[L16 * 40 + quad * 8]);
            float pc = PCs[L16];
#pragma unroll
            for (int kt = 0; kt < 8; ++kt) {
                f32x4 d = __builtin_amdgcn_mfma_f32_16x16x32_f16(bu[kt], ca, (f32x4){0, 0, 0, 0}, 0, 0, 0);
                int idx = L16 * 132 + kt * 16 + quad * 4;
                float4 s = *(const float4*)(&Sp[idx]);
                s.x = fmaf(pc, s.x, d[0]);
                s.y = fmaf(pc, s.y, d[1]);
                s.z = fmaf(pc, s.z, d[2]);
                s.w = fmaf(pc, s.w, d[3]);
                *(float4*)(&Sp[idx]) = s;
                union { f16 e[4]; uint2 u2; } ph;
                ph.e[0] = (f16)s.x; ph.e[1] = (f16)s.y;
                ph.e[2] = (f16)s.z; ph.e[3] = (f16)s.w;
                *(uint2*)(&Sp16[L16 * 136 + kt * 16 + quad * 4]) = ph.u2;
            }
        }
    }
}

// ---------------------------------------------------------------------------
// K6: LayerNorm over head dim, * g, -> f16 for output GEMM
__global__ __launch_bounds__(256) void ln_gate_kernel(
    const float* __restrict__ o_buf, const f16* __restrict__ g16,
    const float* __restrict__ lng, const float* __restrict__ lnb,
    f16* __restrict__ og16)
{
    int row = blockIdx.x;
    int h = threadIdx.x >> 5, lane = threadIdx.x & 31;
    size_t base = (size_t)row * HIDN + h * HD + lane * 4;
    float4 x = *(const float4*)(o_buf + base);
    float s  = x.x + x.y + x.z + x.w;
    float sq = x.x * x.x + x.y * x.y + x.z * x.z + x.w * x.w;
#pragma unroll
    for (int m = 1; m <= 16; m <<= 1) {
        s  += __shfl_xor(s, m);
        sq += __shfl_xor(sq, m);
    }
    float mu  = s * (1.0f / 128.0f);
    float var = sq * (1.0f / 128.0f) - mu * mu;
    float inv = 1.0f / sqrtf(var + 1e-5f);
    int d = lane * 4;
    const float* xp = (const float*)&x;
    union { f16 h4[4]; uint2 u; } pk;
#pragma unroll
    for (int j = 0; j < 4; ++j) {
        float on = (xp[j] - mu) * inv * lng[d + j] + lnb[d + j];
        pk.h4[j] = (f16)(on * (float)g16[base + j]);
    }
    *(uint2*)(og16 + base) = pk.u;
}

// ---------------------------------------------------------------------------
extern "C" void kernel_launch(void* const* d_in, const int* in_sizes, int n_in,
                              void* d_out, int out_size, void* d_ws, size_t ws_size,
                              hipStream_t stream)
{
    (void)in_sizes; (void)n_in; (void)out_size; (void)ws_size;
    const float* x   = (const float*)d_in[0];
    const float* Wq  = (const float*)d_in[1];
    const float* Wk  = (const float*)d_in[2];
    const float* Wv  = (const float*)d_in[3];
    const float* Wa  = (const float*)d_in[4];
    const float* ba  = (const float*)d_in[5];
    const float* Wb  = (const float*)d_in[6];
    const float* bb  = (const float*)d_in[7];
    const float* Wg  = (const float*)d_in[8];
    const float* Wo  = (const float*)d_in[9];
    const float* cqw = (const float*)d_in[10];
    const float* cqb = (const float*)d_in[11];
    const float* ckw = (const float*)d_in[12];
    const float* ckb = (const float*)d_in[13];
    const float* cvw = (const float*)d_in[14];
    const float* cvb = (const float*)d_in[15];
    const float* lng = (const float*)d_in[16];
    const float* lnb = (const float*)d_in[17];
    float* out = (float*)d_out;

    char* ws = (char*)d_ws;
    f16*   x16      = (f16*)(ws + 0);                 //  8,388,608 B
    f16*   WT       = (f16*)(ws + 8388608);           // 12,582,912 B
    f16*   qkvh     = (f16*)(ws + 20971520);          // 25,165,824 B
    f16*   qkv16    = (f16*)(ws + 46137344);          // 25,165,824 B (f16 q,k,v post-conv)
    float* a_buf    = (float*)(ws + 96468992);        // 16,777,216 B
    f16*   g16      = (f16*)(ws + 113246208);         //  8,388,608 B
    float* beta_buf = (float*)(ws + 121634816);       //    131,072 B
    float* o_buf    = (float*)(ws + 121765888);       // 16,777,216 B
    f16*   og16     = (f16*)(ws + 138543104);         //  8,388,608 B

    convert_x_kernel<<<dim3(4096), dim3(256), 0, stream>>>(x, x16);
    transpose_convert_kernel<<<dim3(32, 32, 6), dim3(256), 0, stream>>>(Wq, Wk, Wv, Wa, Wg, Wo, WT);
    gemm_f16<0><<<dim3(40, 32), dim3(256), 0, stream>>>(x16, WT, nullptr, qkvh, a_buf, g16, ba);
    beta_kernel<<<dim3(4096), dim3(256), 0, stream>>>(x, Wb, bb, beta_buf);
    conv_silu_kernel<<<dim3(4096, 3), dim3(256), 0, stream>>>(qkvh, cqw, cqb, ckw, ckb, cvw, cvb, qkv16);
    scan_kernel<<<dim3(16, 8), dim3(64), 0, stream>>>(
        qkv16, qkv16 + XELEMS, qkv16 + 2 * (size_t)XELEMS, a_buf, beta_buf, o_buf);
    ln_gate_kernel<<<dim3(4096), dim3(256), 0, stream>>>(o_buf, g16, lng, lnb, og16);
    gemm_f16<1><<<dim3(8, 32), dim3(256), 0, stream>>>(og16, WT + 5 * (size_t)MAT_ELEMS, out,
                                                       nullptr, nullptr, nullptr, nullptr);
}